// Round 1
// baseline (6057.674 us; speedup 1.0000x reference)
//
#include <hip/hip_runtime.h>
#include <math.h>

#define DEPTH 4
#define HEADS 8
#define DMODEL 512
#define DH 64
#define MF 256
#define FFD 2048
#define SEQN 4096
#define NROWS 8192

static constexpr float DN = 0.35355339059327373f;   // 64^-0.25
static constexpr float RATIO = 0.0625f;             // 256^-0.5
static constexpr float EPSK = 1e-4f;

__device__ __forceinline__ float gelu_exact(float x) {
    return 0.5f * x * (1.0f + erff(x * 0.70710678118654752f));
}

// ---------------- LayerNorm: one block per row ----------------
__global__ __launch_bounds__(256) void ln_kernel(const float* __restrict__ h,
                                                 const float* __restrict__ g,
                                                 const float* __restrict__ b,
                                                 float* __restrict__ y) {
    int row = blockIdx.x, tid = threadIdx.x;
    const float* hr = h + (size_t)row * DMODEL;
    float v0 = hr[tid], v1 = hr[tid + 256];
    __shared__ float s_sum[256], s_sq[256];
    s_sum[tid] = v0 + v1;
    s_sq[tid] = v0 * v0 + v1 * v1;
    __syncthreads();
    for (int off = 128; off > 0; off >>= 1) {
        if (tid < off) { s_sum[tid] += s_sum[tid + off]; s_sq[tid] += s_sq[tid + off]; }
        __syncthreads();
    }
    float mu = s_sum[0] * (1.0f / DMODEL);
    float var = s_sq[0] * (1.0f / DMODEL) - mu * mu;
    float rstd = rsqrtf(var + 1e-5f);
    float* yr = y + (size_t)row * DMODEL;
    yr[tid]       = (v0 - mu) * rstd * g[tid] + b[tid];
    yr[tid + 256] = (v1 - mu) * rstd * g[tid + 256] + b[tid + 256];
}

// ---------------- fp32 tiled GEMM: C[M,N] (+)= act(A[M,K]@W[K,N] + bias) ----------------
// ACT: 0 none, 1 gelu. RES: 0 store, 1 +=
template <int ACT, int RES>
__global__ __launch_bounds__(256) void gemm_kernel(const float* __restrict__ A,
                                                   const float* __restrict__ W,
                                                   const float* __restrict__ bias,
                                                   float* __restrict__ C,
                                                   int N, int K) {
    __shared__ __align__(16) float As[16][68];   // [k][m], stride 68 keeps float4 alignment
    __shared__ __align__(16) float Ws[16][68];   // [k][n]
    int tid = threadIdx.x;
    int tx = tid & 15, ty = tid >> 4;
    int m0 = blockIdx.y * 64, n0 = blockIdx.x * 64;
    float acc[4][4] = {};
    for (int k0 = 0; k0 < K; k0 += 16) {
        {
            int m = tid >> 2, k4 = (tid & 3) * 4;
            float4 av = *(const float4*)(A + (size_t)(m0 + m) * K + k0 + k4);
            As[k4 + 0][m] = av.x; As[k4 + 1][m] = av.y;
            As[k4 + 2][m] = av.z; As[k4 + 3][m] = av.w;
            int k = tid >> 4, n4 = (tid & 15) * 4;
            float4 wv = *(const float4*)(W + (size_t)(k0 + k) * N + n0 + n4);
            *(float4*)&Ws[k][n4] = wv;
        }
        __syncthreads();
#pragma unroll
        for (int kk = 0; kk < 16; kk++) {
            float a[4], w[4];
#pragma unroll
            for (int i = 0; i < 4; i++) a[i] = As[kk][ty * 4 + i];
#pragma unroll
            for (int j = 0; j < 4; j++) w[j] = Ws[kk][tx * 4 + j];
#pragma unroll
            for (int i = 0; i < 4; i++)
#pragma unroll
                for (int j = 0; j < 4; j++) acc[i][j] += a[i] * w[j];
        }
        __syncthreads();
    }
#pragma unroll
    for (int i = 0; i < 4; i++) {
        int row = m0 + ty * 4 + i;
        float* crow = C + (size_t)row * N + n0 + tx * 4;
#pragma unroll
        for (int j = 0; j < 4; j++) {
            float v = acc[i][j] + bias[n0 + tx * 4 + j];
            if (ACT == 1) v = gelu_exact(v);
            if (RES) crow[j] += v; else crow[j] = v;
        }
    }
}

// ---------------- per-(b,h) global max of dd_k : partial pass ----------------
// grid = 16*128 blocks (bh, 32-row tile); block 256
__global__ __launch_bounds__(256) void kmax_part_kernel(const float* __restrict__ qkv,
                                                        const float* __restrict__ proj,
                                                        float* __restrict__ part) {
    int bid = blockIdx.x;
    int bh = bid >> 7, tile = bid & 127;
    int b = bh >> 3, hh = bh & 7;
    int tid = threadIdx.x;
    __shared__ __align__(16) float proj_t[DH * MF];   // [d][m]
    __shared__ __align__(16) float kt[32][DH];
    for (int q = 0; q < 16; q++) {
        int idx = q * 256 + tid;
        float4 pv = *(const float4*)(proj + idx * 4);
        int m = idx >> 4, d0 = (idx & 15) * 4;
        proj_t[(d0 + 0) * MF + m] = pv.x;
        proj_t[(d0 + 1) * MF + m] = pv.y;
        proj_t[(d0 + 2) * MF + m] = pv.z;
        proj_t[(d0 + 3) * MF + m] = pv.w;
    }
    int n0 = tile * 32;
    for (int q = 0; q < 2; q++) {
        int idx = q * 256 + tid;
        int r = idx >> 4, d0 = (idx & 15) * 4;
        *(float4*)&kt[r][d0] =
            *(const float4*)(qkv + (size_t)(b * SEQN + n0 + r) * 1536 + 512 + hh * 64 + d0);
    }
    __syncthreads();
    float mx = -1e30f;
    for (int r = 0; r < 32; r++) {
        float s = 0.f;
#pragma unroll
        for (int d = 0; d < DH; d++) s += kt[r][d] * proj_t[d * MF + tid];
        mx = fmaxf(mx, s * DN);
    }
    __shared__ float red[256];
    red[tid] = mx; __syncthreads();
    for (int off = 128; off > 0; off >>= 1) {
        if (tid < off) red[tid] = fmaxf(red[tid], red[tid + off]);
        __syncthreads();
    }
    if (tid == 0) part[bid] = red[0];
}

__global__ __launch_bounds__(128) void kmax_reduce_kernel(const float* __restrict__ part,
                                                          float* __restrict__ kmax) {
    int bh = blockIdx.x, tid = threadIdx.x;
    __shared__ float red[128];
    red[tid] = part[bh * 128 + tid]; __syncthreads();
    for (int off = 64; off > 0; off >>= 1) {
        if (tid < off) red[tid] = fmaxf(red[tid], red[tid + off]);
        __syncthreads();
    }
    if (tid == 0) kmax[bh] = red[0];
}

// ---------------- ctx = sum_n kp[n,m] v[n,d]; ksum = sum_n kp ----------------
// grid = 16 bh * 16 chunks; block 256 (thread = m)
__global__ __launch_bounds__(256) void ctx_kernel(const float* __restrict__ qkv,
                                                  const float* __restrict__ proj,
                                                  const float* __restrict__ kmax,
                                                  float* __restrict__ ctx,
                                                  float* __restrict__ ksum) {
    int bid = blockIdx.x;
    int bh = bid >> 4, chunk = bid & 15;
    int b = bh >> 3, hh = bh & 7;
    int tid = threadIdx.x;
    __shared__ __align__(16) float proj_t[DH * MF];
    __shared__ __align__(16) float kt[32][DH];
    __shared__ __align__(16) float vt[32][DH];
    __shared__ float diag[32];
    for (int q = 0; q < 16; q++) {
        int idx = q * 256 + tid;
        float4 pv = *(const float4*)(proj + idx * 4);
        int m = idx >> 4, d0 = (idx & 15) * 4;
        proj_t[(d0 + 0) * MF + m] = pv.x;
        proj_t[(d0 + 1) * MF + m] = pv.y;
        proj_t[(d0 + 2) * MF + m] = pv.z;
        proj_t[(d0 + 3) * MF + m] = pv.w;
    }
    float kmx = kmax[bh];
    float acc[DH];
#pragma unroll
    for (int d = 0; d < DH; d++) acc[d] = 0.f;
    float ks = 0.f;
    int base_n = chunk * 256;
    for (int t = 0; t < 8; t++) {
        int n0 = base_n + t * 32;
        __syncthreads();  // previous tile fully consumed (also orders proj_t for t=0)
        for (int q = 0; q < 2; q++) {
            int idx = q * 256 + tid;
            int r = idx >> 4, d0 = (idx & 15) * 4;
            size_t rowb = (size_t)(b * SEQN + n0 + r) * 1536 + hh * 64 + d0;
            *(float4*)&kt[r][d0] = *(const float4*)(qkv + rowb + 512);
            *(float4*)&vt[r][d0] = *(const float4*)(qkv + rowb + 1024);
        }
        __syncthreads();
        if (tid < 32) {
            float s = 0.f;
#pragma unroll
            for (int d = 0; d < DH; d++) s += kt[tid][d] * kt[tid][d];
            diag[tid] = s * 0.5f * DN * DN;
        }
        __syncthreads();
        for (int r = 0; r < 32; r++) {
            float s = 0.f;
#pragma unroll
            for (int d = 0; d < DH; d++) s += kt[r][d] * proj_t[d * MF + tid];
            float kp = RATIO * (expf(s * DN - diag[r] - kmx) + EPSK);
            ks += kp;
#pragma unroll
            for (int d = 0; d < DH; d++) acc[d] += kp * vt[r][d];
        }
    }
    float* crow = ctx + (size_t)bh * MF * DH + tid * DH;
#pragma unroll
    for (int d = 0; d < DH; d++) atomicAdd(&crow[d], acc[d]);
    atomicAdd(&ksum[bh * MF + tid], ks);
}

// ---------------- qp features + d_inv + (qp@ctx)*d_inv ----------------
// grid = 16 bh * 128 tiles of 32 rows; block 256
__global__ __launch_bounds__(256) void qout_kernel(const float* __restrict__ qkv,
                                                   const float* __restrict__ proj,
                                                   const float* __restrict__ ctx,
                                                   const float* __restrict__ ksum,
                                                   float* __restrict__ aout) {
    int bid = blockIdx.x;
    int bh = bid >> 7, tile = bid & 127;
    int b = bh >> 3, hh = bh & 7;
    int tid = threadIdx.x;
    __shared__ __align__(16) float pc[DH * MF];       // proj_t, then reused as ctx[m][d]
    __shared__ __align__(16) float qt[32][68];
    __shared__ float qp_s[32][MF + 1];
    __shared__ float ksum_s[MF];
    __shared__ float red[256];
    __shared__ float rowmax[32], diag[32], dinv[32];
    for (int q = 0; q < 16; q++) {
        int idx = q * 256 + tid;
        float4 pv = *(const float4*)(proj + idx * 4);
        int m = idx >> 4, d0 = (idx & 15) * 4;
        pc[(d0 + 0) * MF + m] = pv.x;
        pc[(d0 + 1) * MF + m] = pv.y;
        pc[(d0 + 2) * MF + m] = pv.z;
        pc[(d0 + 3) * MF + m] = pv.w;
    }
    for (int q = 0; q < 2; q++) {
        int idx = q * 256 + tid;
        int r = idx >> 4, d0 = (idx & 15) * 4;
        *(float4*)&qt[r][d0] =
            *(const float4*)(qkv + (size_t)(b * SEQN + tile * 32 + r) * 1536 + hh * 64 + d0);
    }
    ksum_s[tid] = ksum[bh * MF + tid];
    __syncthreads();
    if (tid < 32) {
        float s = 0.f;
#pragma unroll
        for (int d = 0; d < DH; d++) s += qt[tid][d] * qt[tid][d];
        diag[tid] = s * 0.5f * DN * DN;
    }
    int r = tid >> 3, mb = tid & 7;
    // phase 1: dd, row max
    float lmax = -1e30f;
    for (int j = 0; j < 32; j++) {
        int m = mb + j * 8;
        float s = 0.f;
#pragma unroll
        for (int d = 0; d < DH; d++) s += qt[r][d] * pc[d * MF + m];
        s *= DN;
        qp_s[r][m] = s;
        lmax = fmaxf(lmax, s);
    }
    red[tid] = lmax; __syncthreads();
    if (tid < 32) {
        float mm = red[tid * 8];
#pragma unroll
        for (int j = 1; j < 8; j++) mm = fmaxf(mm, red[tid * 8 + j]);
        rowmax[tid] = mm;
    }
    __syncthreads();
    // phase 2: qp, d_inv
    float dg = diag[r], rm = rowmax[r];
    float dsum = 0.f;
    for (int j = 0; j < 32; j++) {
        int m = mb + j * 8;
        float v = RATIO * (expf(qp_s[r][m] - dg - rm) + EPSK);
        qp_s[r][m] = v;
        dsum += v * ksum_s[m];
    }
    red[tid] = dsum; __syncthreads();
    if (tid < 32) {
        float ssum = 0.f;
#pragma unroll
        for (int j = 0; j < 8; j++) ssum += red[tid * 8 + j];
        dinv[tid] = 1.0f / ssum;
    }
    __syncthreads();
    // load ctx into pc (proj no longer needed)
    {
        const float4* csrc = (const float4*)(ctx + (size_t)bh * MF * DH);
        float4* cdst = (float4*)pc;
        for (int q = 0; q < 16; q++) cdst[q * 256 + tid] = csrc[q * 256 + tid];
    }
    __syncthreads();
    // phase 3: out = (qp @ ctx) * dinv
    int d0 = (tid & 7) * 8;
    float o[8] = {};
    for (int m = 0; m < MF; m++) {
        float qv = qp_s[r][m];
#pragma unroll
        for (int j = 0; j < 8; j++) o[j] += qv * pc[m * DH + d0 + j];
    }
    float di = dinv[r];
    float* orow = aout + (size_t)(b * SEQN + tile * 32 + r) * DMODEL + hh * 64 + d0;
#pragma unroll
    for (int j = 0; j < 8; j++) orow[j] = o[j] * di;
}

extern "C" void kernel_launch(void* const* d_in, const int* in_sizes, int n_in,
                              void* d_out, int out_size, void* d_ws, size_t ws_size,
                              hipStream_t stream) {
    const float* x     = (const float*)d_in[0];
    const float* proj  = (const float*)d_in[1];
    const float* ln1_g = (const float*)d_in[2];
    const float* ln1_b = (const float*)d_in[3];
    const float* Wqkv  = (const float*)d_in[4];
    const float* bqkv  = (const float*)d_in[5];
    const float* Wo    = (const float*)d_in[6];
    const float* bo    = (const float*)d_in[7];
    const float* ln2_g = (const float*)d_in[8];
    const float* ln2_b = (const float*)d_in[9];
    const float* Wff1  = (const float*)d_in[10];
    const float* bff1  = (const float*)d_in[11];
    const float* Wff2  = (const float*)d_in[12];
    const float* bff2  = (const float*)d_in[13];

    float* h  = (float*)d_out;            // [8192, 512], final output layout matches
    float* ws = (float*)d_ws;
    float* y     = ws;                    //  4,194,304 (LN out)
    float* qkv   = ws + 4194304;          // 12,582,912
    float* abuf  = ws + 16777216;         //  4,194,304 (attn concat out)
    float* ffmid = ws + 4194304;          // 16,777,216 (aliases qkv+abuf, both dead by then)
    float* ctxb  = ws + 20971520;         //    262,144
    float* ksum  = ws + 21233664;         //      4,096
    float* kmax  = ws + 21237760;         //         16
    float* kpart = ws + 21237776;         //      2,048   total ≈ 85 MB

    hipMemcpyAsync(h, x, (size_t)NROWS * DMODEL * sizeof(float),
                   hipMemcpyDeviceToDevice, stream);

    for (int i = 0; i < DEPTH; i++) {
        const float* pj = proj + (size_t)i * MF * DH;
        ln_kernel<<<NROWS, 256, 0, stream>>>(h, ln1_g + i * DMODEL, ln1_b + i * DMODEL, y);
        gemm_kernel<0, 0><<<dim3(1536 / 64, NROWS / 64), 256, 0, stream>>>(
            y, Wqkv + (size_t)i * DMODEL * 1536, bqkv + i * 1536, qkv, 1536, DMODEL);
        kmax_part_kernel<<<16 * 128, 256, 0, stream>>>(qkv, pj, kpart);
        kmax_reduce_kernel<<<16, 128, 0, stream>>>(kpart, kmax);
        hipMemsetAsync(ctxb, 0, (size_t)(16 * MF * DH + 16 * MF) * sizeof(float), stream);
        ctx_kernel<<<16 * 16, 256, 0, stream>>>(qkv, pj, kmax, ctxb, ksum);
        qout_kernel<<<16 * 128, 256, 0, stream>>>(qkv, pj, ctxb, ksum, abuf);
        gemm_kernel<0, 1><<<dim3(DMODEL / 64, NROWS / 64), 256, 0, stream>>>(
            abuf, Wo + (size_t)i * DMODEL * DMODEL, bo + i * DMODEL, h, DMODEL, DMODEL);
        ln_kernel<<<NROWS, 256, 0, stream>>>(h, ln2_g + i * DMODEL, ln2_b + i * DMODEL, y);
        gemm_kernel<1, 0><<<dim3(FFD / 64, NROWS / 64), 256, 0, stream>>>(
            y, Wff1 + (size_t)i * DMODEL * FFD, bff1 + i * FFD, ffmid, FFD, DMODEL);
        gemm_kernel<0, 1><<<dim3(DMODEL / 64, NROWS / 64), 256, 0, stream>>>(
            ffmid, Wff2 + (size_t)i * FFD * DMODEL, bff2 + i * DMODEL, h, DMODEL, FFD);
    }
}

// Round 2
// 2874.424 us; speedup vs baseline: 2.1074x; 2.1074x over previous
//
#include <hip/hip_runtime.h>
#include <math.h>

#define DEPTH 4
#define DMODEL 512
#define DH 64
#define MF 256
#define FFD 2048
#define SEQN 4096
#define NROWS 8192

typedef __bf16 bf16_t;
typedef bf16_t bf16x8 __attribute__((ext_vector_type(8)));
typedef float f32x4v __attribute__((ext_vector_type(4)));

static constexpr float DN = 0.35355339059327373f;   // 64^-0.25
static constexpr float RATIO = 0.0625f;             // 256^-0.5
static constexpr float EPSK = 1e-4f;

__device__ __forceinline__ float gelu_exact(float x) {
    return 0.5f * x * (1.0f + erff(x * 0.70710678118654752f));
}

#define AS1(p) ((const __attribute__((address_space(1))) void*)(p))
#define AS3(p) ((__attribute__((address_space(3))) void*)(p))

// ---------------- LayerNorm -> bf16 ----------------
__global__ __launch_bounds__(256) void ln_kernel(const float* __restrict__ h,
                                                 const float* __restrict__ g,
                                                 const float* __restrict__ b,
                                                 bf16_t* __restrict__ y) {
    int row = blockIdx.x, tid = threadIdx.x;
    const float* hr = h + (size_t)row * DMODEL;
    float v0 = hr[tid], v1 = hr[tid + 256];
    __shared__ float s_sum[256], s_sq[256];
    s_sum[tid] = v0 + v1;
    s_sq[tid] = v0 * v0 + v1 * v1;
    __syncthreads();
    for (int off = 128; off > 0; off >>= 1) {
        if (tid < off) { s_sum[tid] += s_sum[tid + off]; s_sq[tid] += s_sq[tid + off]; }
        __syncthreads();
    }
    float mu = s_sum[0] * (1.0f / DMODEL);
    float var = s_sq[0] * (1.0f / DMODEL) - mu * mu;
    float rstd = rsqrtf(var + 1e-5f);
    bf16_t* yr = y + (size_t)row * DMODEL;
    yr[tid]       = (bf16_t)((v0 - mu) * rstd * g[tid] + b[tid]);
    yr[tid + 256] = (bf16_t)((v1 - mu) * rstd * g[tid + 256] + b[tid + 256]);
}

// ---------------- weight transpose + bf16 convert: Wt[N][K] = (bf16)W[K][N] ----------------
__global__ __launch_bounds__(256) void wconv_kernel(const float* __restrict__ W,
                                                    bf16_t* __restrict__ Wt, int K, int N) {
    __shared__ float t[32][33];
    int n0 = blockIdx.x * 32, k0 = blockIdx.y * 32;
    int tx = threadIdx.x & 31, ty = threadIdx.x >> 5;
#pragma unroll
    for (int i = 0; i < 32; i += 8)
        t[ty + i][tx] = W[(size_t)(k0 + ty + i) * N + n0 + tx];
    __syncthreads();
#pragma unroll
    for (int i = 0; i < 32; i += 8)
        Wt[(size_t)(n0 + ty + i) * K + k0 + tx] = (bf16_t)t[tx][ty + i];
}

// ---------------- MFMA GEMM: C[M,N] = act(A[M,K] @ Wt[N,K]^T + bias) ----------------
// 128x128 tile, BK=32, 4 waves (2x2 of 64x64), 16x16x32 bf16 MFMA
template <int ACT, int RES, int WF, int WB>
__global__ __launch_bounds__(256) void gemm_mfma(const bf16_t* __restrict__ A,
                                                 const bf16_t* __restrict__ Bt,
                                                 const float* __restrict__ bias,
                                                 float* __restrict__ Cf,
                                                 bf16_t* __restrict__ Cb,
                                                 int N, int K) {
    __shared__ __attribute__((aligned(16))) bf16_t As[128 * 32];
    __shared__ __attribute__((aligned(16))) bf16_t Bs[128 * 32];
    int tid = threadIdx.x;
    int wv = tid >> 6, ln = tid & 63;
    int m0 = blockIdx.y * 128, n0 = blockIdx.x * 128;
    int wr = (wv >> 1) * 64, wc = (wv & 1) * 64;
    f32x4v acc[4][4] = {};
    int lr = ln & 15, kq = (ln >> 4) * 8;
    for (int k0 = 0; k0 < K; k0 += 32) {
        __syncthreads();
        {
            int c0 = 2 * wv;
#pragma unroll
            for (int q = 0; q < 2; q++) {
                int c = c0 + q;
                int row = c * 16 + (ln >> 2);
                int kk = k0 + (ln & 3) * 8;
                __builtin_amdgcn_global_load_lds(AS1(A + (size_t)(m0 + row) * K + kk),
                                                 AS3(&As[c * 512]), 16, 0, 0);
                __builtin_amdgcn_global_load_lds(AS1(Bt + (size_t)(n0 + row) * K + kk),
                                                 AS3(&Bs[c * 512]), 16, 0, 0);
            }
        }
        __syncthreads();
        bf16x8 af[4], bfr[4];
#pragma unroll
        for (int m = 0; m < 4; m++)
            af[m] = *(const bf16x8*)&As[(wr + m * 16 + lr) * 32 + kq];
#pragma unroll
        for (int n = 0; n < 4; n++)
            bfr[n] = *(const bf16x8*)&Bs[(wc + n * 16 + lr) * 32 + kq];
#pragma unroll
        for (int m = 0; m < 4; m++)
#pragma unroll
            for (int n = 0; n < 4; n++)
                acc[m][n] = __builtin_amdgcn_mfma_f32_16x16x32_bf16(af[m], bfr[n], acc[m][n], 0, 0, 0);
    }
    int rq = (ln >> 4) * 4;
#pragma unroll
    for (int n = 0; n < 4; n++) {
        int col = n0 + wc + n * 16 + lr;
        float bcol = bias[col];
#pragma unroll
        for (int m = 0; m < 4; m++) {
#pragma unroll
            for (int r = 0; r < 4; r++) {
                int row = m0 + wr + m * 16 + rq + r;
                float v = acc[m][n][r] + bcol;
                if (ACT == 1) v = gelu_exact(v);
                size_t idx = (size_t)row * N + col;
                if (RES) Cf[idx] += v;
                else if (WF) Cf[idx] = v;
                if (WB) Cb[idx] = (bf16_t)v;
            }
        }
    }
}

// ---------------- helpers for feature kernels ----------------
__device__ __forceinline__ void stage_row8(const bf16_t* src, float* dst) {
    bf16x8 v = *(const bf16x8*)src;
    float4 a, b2;
    a.x = (float)v[0]; a.y = (float)v[1]; a.z = (float)v[2]; a.w = (float)v[3];
    b2.x = (float)v[4]; b2.y = (float)v[5]; b2.z = (float)v[6]; b2.w = (float)v[7];
    *(float4*)dst = a;
    *(float4*)(dst + 4) = b2;
}

// ---------------- kmax partial: grid 16 bh x 32 chunks (128 rows), thread=m ----------------
__global__ __launch_bounds__(256) void kmax_part_kernel(const bf16_t* __restrict__ qkv,
                                                        const float* __restrict__ proj,
                                                        float* __restrict__ part) {
    int bid = blockIdx.x;
    int bh = bid >> 5, chunk = bid & 31;
    int b = bh >> 3, hh = bh & 7;
    int tid = threadIdx.x;
    __shared__ __attribute__((aligned(16))) float kt[32][64];
    float4 preg[16];
    {
        const float4* pr = (const float4*)(proj + tid * 64);
#pragma unroll
        for (int i = 0; i < 16; i++) preg[i] = pr[i];
    }
    float mx = -1e30f;
    for (int t = 0; t < 4; t++) {
        int n0 = chunk * 128 + t * 32;
        __syncthreads();
        {
            int r = tid >> 3, d0 = (tid & 7) * 8;
            stage_row8(qkv + (size_t)(b * SEQN + n0 + r) * 1536 + 512 + hh * 64 + d0, &kt[r][d0]);
        }
        __syncthreads();
        for (int r = 0; r < 32; r++) {
            const float4* krow = (const float4*)kt[r];
            float s = 0.f;
#pragma unroll
            for (int i = 0; i < 16; i++) {
                float4 k4 = krow[i];
                s += k4.x * preg[i].x + k4.y * preg[i].y + k4.z * preg[i].z + k4.w * preg[i].w;
            }
            mx = fmaxf(mx, s * DN);
        }
    }
    __shared__ float red[256];
    red[tid] = mx; __syncthreads();
    for (int off = 128; off > 0; off >>= 1) {
        if (tid < off) red[tid] = fmaxf(red[tid], red[tid + off]);
        __syncthreads();
    }
    if (tid == 0) part[bid] = red[0];
}

__global__ __launch_bounds__(64) void kmax_reduce_kernel(const float* __restrict__ part,
                                                         float* __restrict__ kmax) {
    int bh = blockIdx.x, tid = threadIdx.x;
    float v = (tid < 32) ? part[bh * 32 + tid] : -1e30f;
#pragma unroll
    for (int off = 16; off > 0; off >>= 1) v = fmaxf(v, __shfl_down(v, off));
    if (tid == 0) kmax[bh] = v;
}

// ---------------- ctx partial: grid 16 bh x 16 chunks (256 rows), thread=m ----------------
__global__ __launch_bounds__(256) void ctx_kernel(const bf16_t* __restrict__ qkv,
                                                  const float* __restrict__ proj,
                                                  const float* __restrict__ kmax,
                                                  float* __restrict__ ctx_part,
                                                  float* __restrict__ ksum_part) {
    int bid = blockIdx.x;
    int bh = bid >> 4, chunk = bid & 15;
    int b = bh >> 3, hh = bh & 7;
    int tid = threadIdx.x;
    __shared__ __attribute__((aligned(16))) float kt[32][64];
    __shared__ __attribute__((aligned(16))) float vt[32][64];
    __shared__ float diag[32];
    float4 preg[16];
    {
        const float4* pr = (const float4*)(proj + tid * 64);
#pragma unroll
        for (int i = 0; i < 16; i++) preg[i] = pr[i];
    }
    float kmx = kmax[bh];
    float4 acc[16] = {};
    float ks = 0.f;
    for (int t = 0; t < 8; t++) {
        int n0 = chunk * 256 + t * 32;
        __syncthreads();
        {
            int r = tid >> 3, d0 = (tid & 7) * 8;
            size_t rowb = (size_t)(b * SEQN + n0 + r) * 1536 + hh * 64 + d0;
            stage_row8(qkv + rowb + 512, &kt[r][d0]);
            stage_row8(qkv + rowb + 1024, &vt[r][d0]);
        }
        __syncthreads();
        if (tid < 32) {
            const float4* krow = (const float4*)kt[tid];
            float s = 0.f;
#pragma unroll
            for (int i = 0; i < 16; i++) {
                float4 k4 = krow[i];
                s += k4.x * k4.x + k4.y * k4.y + k4.z * k4.z + k4.w * k4.w;
            }
            diag[tid] = s * 0.5f * DN * DN;
        }
        __syncthreads();
        for (int r = 0; r < 32; r++) {
            const float4* krow = (const float4*)kt[r];
            float s = 0.f;
#pragma unroll
            for (int i = 0; i < 16; i++) {
                float4 k4 = krow[i];
                s += k4.x * preg[i].x + k4.y * preg[i].y + k4.z * preg[i].z + k4.w * preg[i].w;
            }
            float kp = RATIO * (expf(s * DN - diag[r] - kmx) + EPSK);
            ks += kp;
            const float4* vrow = (const float4*)vt[r];
#pragma unroll
            for (int i = 0; i < 16; i++) {
                float4 v4 = vrow[i];
                acc[i].x += kp * v4.x; acc[i].y += kp * v4.y;
                acc[i].z += kp * v4.z; acc[i].w += kp * v4.w;
            }
        }
    }
    float4* cp = (float4*)(ctx_part + ((size_t)(chunk * 16 + bh) * 256 + tid) * 64);
#pragma unroll
    for (int i = 0; i < 16; i++) cp[i] = acc[i];
    ksum_part[(chunk * 16 + bh) * 256 + tid] = ks;
}

// ---------------- partial reduce (16 chunks) ----------------
__global__ __launch_bounds__(256) void part_reduce_kernel(const float* __restrict__ part,
                                                          float* __restrict__ out, int stride) {
    int i = blockIdx.x * 256 + threadIdx.x;
    float s = 0.f;
#pragma unroll
    for (int c = 0; c < 16; c++) s += part[(size_t)c * stride + i];
    out[i] = s;
}

// ---------------- qp features + d_inv + (qp@ctx)*d_inv -> bf16 ----------------
__global__ __launch_bounds__(256) void qout_kernel(const bf16_t* __restrict__ qkv,
                                                   const float* __restrict__ proj,
                                                   const float* __restrict__ ctx,
                                                   const float* __restrict__ ksum,
                                                   bf16_t* __restrict__ aout) {
    int bid = blockIdx.x;
    int bh = bid >> 7, tile = bid & 127;
    int b = bh >> 3, hh = bh & 7;
    int tid = threadIdx.x;
    __shared__ __attribute__((aligned(16))) float qt[32][68];
    __shared__ float qp_s[32][MF + 1];
    __shared__ float ksum_s[MF];
    __shared__ float red[256];
    __shared__ float rowmax[32], diag[32], dinv[32];
    float4 preg[16];
    {
        const float4* pr = (const float4*)(proj + tid * 64);
#pragma unroll
        for (int i = 0; i < 16; i++) preg[i] = pr[i];
    }
    {
        int r = tid >> 3, d0 = (tid & 7) * 8;
        stage_row8(qkv + (size_t)(b * SEQN + tile * 32 + r) * 1536 + hh * 64 + d0, &qt[r][d0]);
    }
    ksum_s[tid] = ksum[bh * MF + tid];
    __syncthreads();
    if (tid < 32) {
        const float4* qrow = (const float4*)qt[tid];
        float s = 0.f;
#pragma unroll
        for (int i = 0; i < 16; i++) {
            float4 q4 = qrow[i];
            s += q4.x * q4.x + q4.y * q4.y + q4.z * q4.z + q4.w * q4.w;
        }
        diag[tid] = s * 0.5f * DN * DN;
    }
    // phase 1: dd (thread = m, loop rows)
    for (int r = 0; r < 32; r++) {
        const float4* qrow = (const float4*)qt[r];
        float s = 0.f;
#pragma unroll
        for (int i = 0; i < 16; i++) {
            float4 q4 = qrow[i];
            s += q4.x * preg[i].x + q4.y * preg[i].y + q4.z * preg[i].z + q4.w * preg[i].w;
        }
        qp_s[r][tid] = s * DN;
    }
    __syncthreads();
    int r = tid >> 3, mb = tid & 7;
    float lmax = -1e30f;
    for (int j = 0; j < 32; j++) lmax = fmaxf(lmax, qp_s[r][mb + j * 8]);
    red[tid] = lmax; __syncthreads();
    if (tid < 32) {
        float mm = red[tid * 8];
#pragma unroll
        for (int j = 1; j < 8; j++) mm = fmaxf(mm, red[tid * 8 + j]);
        rowmax[tid] = mm;
    }
    __syncthreads();
    float dg = diag[r], rm = rowmax[r];
    float dsum = 0.f;
    for (int j = 0; j < 32; j++) {
        int m = mb + j * 8;
        float v = RATIO * (expf(qp_s[r][m] - dg - rm) + EPSK);
        qp_s[r][m] = v;
        dsum += v * ksum_s[m];
    }
    red[tid] = dsum; __syncthreads();
    if (tid < 32) {
        float ssum = 0.f;
#pragma unroll
        for (int j = 0; j < 8; j++) ssum += red[tid * 8 + j];
        dinv[tid] = 1.0f / ssum;
    }
    __syncthreads();
    // phase 3: out = (qp @ ctx) * dinv, ctx from global (L1/L2 resident)
    int d0 = (tid & 7) * 8;
    float o[8] = {};
    const float* cb = ctx + (size_t)bh * MF * DH;
    for (int m = 0; m < MF; m++) {
        float qv = qp_s[r][m];
        const float4* cv = (const float4*)(cb + m * 64 + d0);
        float4 c0 = cv[0], c1 = cv[1];
        o[0] += qv * c0.x; o[1] += qv * c0.y; o[2] += qv * c0.z; o[3] += qv * c0.w;
        o[4] += qv * c1.x; o[5] += qv * c1.y; o[6] += qv * c1.z; o[7] += qv * c1.w;
    }
    float di = dinv[r];
    bf16x8 ov;
#pragma unroll
    for (int j = 0; j < 8; j++) ov[j] = (bf16_t)(o[j] * di);
    *(bf16x8*)(aout + (size_t)(b * SEQN + tile * 32 + r) * DMODEL + hh * 64 + d0) = ov;
}

extern "C" void kernel_launch(void* const* d_in, const int* in_sizes, int n_in,
                              void* d_out, int out_size, void* d_ws, size_t ws_size,
                              hipStream_t stream) {
    const float* x     = (const float*)d_in[0];
    const float* proj  = (const float*)d_in[1];
    const float* ln1_g = (const float*)d_in[2];
    const float* ln1_b = (const float*)d_in[3];
    const float* Wqkv  = (const float*)d_in[4];
    const float* bqkv  = (const float*)d_in[5];
    const float* Wo    = (const float*)d_in[6];
    const float* bo    = (const float*)d_in[7];
    const float* ln2_g = (const float*)d_in[8];
    const float* ln2_b = (const float*)d_in[9];
    const float* Wff1  = (const float*)d_in[10];
    const float* bff1  = (const float*)d_in[11];
    const float* Wff2  = (const float*)d_in[12];
    const float* bff2  = (const float*)d_in[13];

    float* h = (float*)d_out;
    char* ws = (char*)d_ws;
    bf16_t* ybf   = (bf16_t*)(ws);                       //  8 MB
    bf16_t* qkvb  = (bf16_t*)(ws + 8388608);             // 24 MB
    char*   shr   = ws + 33554432;                       // 32 MB shared region
    float*  ctx_part  = (float*)(shr);                   // 16 MB (dead before abuf/ffmid)
    float*  ksum_part = (float*)(shr + 16777216);        // 256 KB
    bf16_t* abufb = (bf16_t*)(shr);                      //  8 MB (dead before ffmid)
    bf16_t* ffmidb = (bf16_t*)(shr);                     // 32 MB
    bf16_t* wq_t  = (bf16_t*)(ws + 67108864);            // 1.5 MB  [1536][512]
    bf16_t* wo_t  = (bf16_t*)(ws + 68681728);            // 512 KB  [512][512]
    bf16_t* w1_t  = (bf16_t*)(ws + 69206016);            // 2 MB    [2048][512]
    bf16_t* w2_t  = (bf16_t*)(ws + 71303168);            // 2 MB    [512][2048]
    float*  ctxb  = (float*)(ws + 73400320);             // 1 MB
    float*  ksumb = (float*)(ws + 74448896);             // 16 KB
    float*  kpart = (float*)(ws + 74465280);             // 2 KB
    float*  kmaxb = (float*)(ws + 74467328);             // 64 B

    hipMemcpyAsync(h, x, (size_t)NROWS * DMODEL * sizeof(float),
                   hipMemcpyDeviceToDevice, stream);

    for (int i = 0; i < DEPTH; i++) {
        const float* pj = proj + (size_t)i * MF * DH;
        wconv_kernel<<<dim3(1536 / 32, 512 / 32), 256, 0, stream>>>(
            Wqkv + (size_t)i * DMODEL * 1536, wq_t, 512, 1536);
        wconv_kernel<<<dim3(512 / 32, 512 / 32), 256, 0, stream>>>(
            Wo + (size_t)i * DMODEL * DMODEL, wo_t, 512, 512);
        wconv_kernel<<<dim3(2048 / 32, 512 / 32), 256, 0, stream>>>(
            Wff1 + (size_t)i * DMODEL * FFD, w1_t, 512, 2048);
        wconv_kernel<<<dim3(512 / 32, 2048 / 32), 256, 0, stream>>>(
            Wff2 + (size_t)i * FFD * DMODEL, w2_t, 2048, 512);

        ln_kernel<<<NROWS, 256, 0, stream>>>(h, ln1_g + i * DMODEL, ln1_b + i * DMODEL, ybf);
        gemm_mfma<0, 0, 0, 1><<<dim3(1536 / 128, NROWS / 128), 256, 0, stream>>>(
            ybf, wq_t, bqkv + i * 1536, nullptr, qkvb, 1536, 512);
        kmax_part_kernel<<<16 * 32, 256, 0, stream>>>(qkvb, pj, kpart);
        kmax_reduce_kernel<<<16, 64, 0, stream>>>(kpart, kmaxb);
        ctx_kernel<<<16 * 16, 256, 0, stream>>>(qkvb, pj, kmaxb, ctx_part, ksum_part);
        part_reduce_kernel<<<(16 * MF * DH) / 256, 256, 0, stream>>>(ctx_part, ctxb, 16 * MF * DH);
        part_reduce_kernel<<<(16 * MF) / 256, 256, 0, stream>>>(ksum_part, ksumb, 16 * MF);
        qout_kernel<<<16 * 128, 256, 0, stream>>>(qkvb, pj, ctxb, ksumb, abufb);
        gemm_mfma<0, 1, 1, 0><<<dim3(512 / 128, NROWS / 128), 256, 0, stream>>>(
            abufb, wo_t, bo + i * DMODEL, h, nullptr, 512, 512);

        ln_kernel<<<NROWS, 256, 0, stream>>>(h, ln2_g + i * DMODEL, ln2_b + i * DMODEL, ybf);
        gemm_mfma<1, 0, 0, 1><<<dim3(2048 / 128, NROWS / 128), 256, 0, stream>>>(
            ybf, w1_t, bff1 + i * FFD, nullptr, ffmidb, 2048, 512);
        gemm_mfma<0, 1, 1, 0><<<dim3(512 / 128, NROWS / 128), 256, 0, stream>>>(
            ffmidb, w2_t, bff2 + i * DMODEL, h, nullptr, 512, 2048);
    }
}

// Round 3
// 1166.427 us; speedup vs baseline: 5.1934x; 2.4643x over previous
//
#include <hip/hip_runtime.h>
#include <math.h>

#define DEPTH 4
#define DMODEL 512
#define DH 64
#define MF 256
#define FFD 2048
#define SEQN 4096
#define NROWS 8192

typedef __bf16 bf16_t;
typedef bf16_t bf16x8 __attribute__((ext_vector_type(8)));
typedef bf16_t bf16x4 __attribute__((ext_vector_type(4)));
typedef float f32x4v __attribute__((ext_vector_type(4)));

static constexpr float DN = 0.35355339059327373f;   // 64^-0.25
static constexpr float RATIO = 0.0625f;             // 256^-0.5
static constexpr float EPSK = 1e-4f;

__device__ __forceinline__ float gelu_exact(float x) {
    return 0.5f * x * (1.0f + erff(x * 0.70710678118654752f));
}

#define AS1(p) ((const __attribute__((address_space(1))) void*)(p))
#define AS3(p) ((__attribute__((address_space(3))) void*)(p))

// ---------------- LayerNorm -> bf16 ----------------
__global__ __launch_bounds__(256) void ln_kernel(const float* __restrict__ h,
                                                 const float* __restrict__ g,
                                                 const float* __restrict__ b,
                                                 bf16_t* __restrict__ y) {
    int row = blockIdx.x, tid = threadIdx.x;
    const float* hr = h + (size_t)row * DMODEL;
    float v0 = hr[tid], v1 = hr[tid + 256];
    __shared__ float s_sum[256], s_sq[256];
    s_sum[tid] = v0 + v1;
    s_sq[tid] = v0 * v0 + v1 * v1;
    __syncthreads();
    for (int off = 128; off > 0; off >>= 1) {
        if (tid < off) { s_sum[tid] += s_sum[tid + off]; s_sq[tid] += s_sq[tid + off]; }
        __syncthreads();
    }
    float mu = s_sum[0] * (1.0f / DMODEL);
    float var = s_sq[0] * (1.0f / DMODEL) - mu * mu;
    float rstd = rsqrtf(var + 1e-5f);
    bf16_t* yr = y + (size_t)row * DMODEL;
    yr[tid]       = (bf16_t)((v0 - mu) * rstd * g[tid] + b[tid]);
    yr[tid + 256] = (bf16_t)((v1 - mu) * rstd * g[tid + 256] + b[tid + 256]);
}

// ---------------- weight transpose + bf16 convert: Wt[N][K] = (bf16)W[K][N] ----------------
__global__ __launch_bounds__(256) void wconv_kernel(const float* __restrict__ W,
                                                    bf16_t* __restrict__ Wt, int K, int N) {
    __shared__ float t[32][33];
    int n0 = blockIdx.x * 32, k0 = blockIdx.y * 32;
    int tx = threadIdx.x & 31, ty = threadIdx.x >> 5;
#pragma unroll
    for (int i = 0; i < 32; i += 8)
        t[ty + i][tx] = W[(size_t)(k0 + ty + i) * N + n0 + tx];
    __syncthreads();
#pragma unroll
    for (int i = 0; i < 32; i += 8)
        Wt[(size_t)(n0 + ty + i) * K + k0 + tx] = (bf16_t)t[tx][ty + i];
}

// ---------------- proj -> bf16 (no transpose; proj is [m][dh] = [N][K]) ----------------
__global__ __launch_bounds__(256) void pconv_kernel(const float* __restrict__ proj,
                                                    bf16_t* __restrict__ projb) {
    int i = (blockIdx.x * 256 + threadIdx.x) * 4;
    float4 v = *(const float4*)(proj + i);
    bf16x4 o;
    o[0] = (bf16_t)v.x; o[1] = (bf16_t)v.y; o[2] = (bf16_t)v.z; o[3] = (bf16_t)v.w;
    *(bf16x4*)(projb + i) = o;
}

// ---------------- MFMA GEMM: C[M,N] = act(A[M,K] @ Bt[N,K]^T + bias) ----------------
// 128x128 tile, BK=32, 4 waves (2x2 of 64x64), 16x16x32 bf16 MFMA
// QKVE: qkv-special epilogue (Q,K -> qkvb stride 1024; V -> Vt[bh*64+d][n] transposed)
template <int ACT, int RES, int WF, int WB, int QKVE>
__global__ __launch_bounds__(256) void gemm_mfma(const bf16_t* __restrict__ A,
                                                 const bf16_t* __restrict__ Bt,
                                                 const float* __restrict__ bias,
                                                 float* __restrict__ Cf,
                                                 bf16_t* __restrict__ Cb,
                                                 bf16_t* __restrict__ Vt,
                                                 int N, int K) {
    __shared__ __attribute__((aligned(16))) bf16_t As[128 * 32];
    __shared__ __attribute__((aligned(16))) bf16_t Bs[128 * 32];
    int tid = threadIdx.x;
    int wv = tid >> 6, ln = tid & 63;
    int m0 = blockIdx.y * 128, n0 = blockIdx.x * 128;
    int wr = (wv >> 1) * 64, wc = (wv & 1) * 64;
    f32x4v acc[4][4] = {};
    int lr = ln & 15, kq = (ln >> 4) * 8;
    for (int k0 = 0; k0 < K; k0 += 32) {
        __syncthreads();
        {
            int c0 = 2 * wv;
#pragma unroll
            for (int q = 0; q < 2; q++) {
                int c = c0 + q;
                int row = c * 16 + (ln >> 2);
                int kk = k0 + (ln & 3) * 8;
                __builtin_amdgcn_global_load_lds(AS1(A + (size_t)(m0 + row) * K + kk),
                                                 AS3(&As[c * 512]), 16, 0, 0);
                __builtin_amdgcn_global_load_lds(AS1(Bt + (size_t)(n0 + row) * K + kk),
                                                 AS3(&Bs[c * 512]), 16, 0, 0);
            }
        }
        __syncthreads();
        bf16x8 af[4], bfr[4];
#pragma unroll
        for (int m = 0; m < 4; m++)
            af[m] = *(const bf16x8*)&As[(wr + m * 16 + lr) * 32 + kq];
#pragma unroll
        for (int n = 0; n < 4; n++)
            bfr[n] = *(const bf16x8*)&Bs[(wc + n * 16 + lr) * 32 + kq];
#pragma unroll
        for (int m = 0; m < 4; m++)
#pragma unroll
            for (int n = 0; n < 4; n++)
                acc[m][n] = __builtin_amdgcn_mfma_f32_16x16x32_bf16(af[m], bfr[n], acc[m][n], 0, 0, 0);
    }
    int rq = (ln >> 4) * 4;
#pragma unroll
    for (int n = 0; n < 4; n++) {
        int col = n0 + wc + n * 16 + lr;
        float bcol = bias[col];
#pragma unroll
        for (int m = 0; m < 4; m++) {
#pragma unroll
            for (int r = 0; r < 4; r++) {
                int row = m0 + wr + m * 16 + rq + r;
                float v = acc[m][n][r] + bcol;
                if (ACT == 1) v = gelu_exact(v);
                if (QKVE) {
                    int bb = row >> 12, nn = row & 4095;
                    if (col < 1024) {
                        Cb[(size_t)row * 1024 + col] = (bf16_t)v;
                    } else {
                        int hh2 = (col >> 6) & 7, dd2 = col & 63;
                        Vt[(((size_t)bb * 8 + hh2) * 64 + dd2) * 4096 + nn] = (bf16_t)v;
                    }
                } else {
                    size_t idx = (size_t)row * N + col;
                    if (RES) Cf[idx] += v;
                    else if (WF) Cf[idx] = v;
                    if (WB) Cb[idx] = (bf16_t)v;
                }
            }
        }
    }
}

// ---------------- FAVOR+ feature GEMM: dd[128n x 256m] per block, K=64 ----------------
// MODE 0 = Q (rowmax+exp -> QP[bh][n][m] bf16)
// MODE 1 = K max pass (block max of dd -> kpart)
// MODE 2 = K write pass (exp with kmx -> KPt[bh][m][n] bf16, transposed)
template <int MODE>
__global__ __launch_bounds__(256) void feat_kernel(const bf16_t* __restrict__ qkvb,
                                                   const bf16_t* __restrict__ projb,
                                                   const float* __restrict__ kmaxb,
                                                   bf16_t* __restrict__ outp,
                                                   float* __restrict__ kpart) {
    int bid = blockIdx.x;
    int bh = bid >> 5, tile = bid & 31;
    int b = bh >> 3, hh = bh & 7;
    int tid = threadIdx.x, wv = tid >> 6, ln = tid & 63;
    __shared__ __attribute__((aligned(16))) bf16_t As[128 * 64];
    __shared__ __attribute__((aligned(16))) bf16_t Bs[256 * 64];
    __shared__ float diag_s[128];
    __shared__ float rmx_s[2][128];
    __shared__ float red_s[256];
    int n0 = tile * 128;
    int qoff = (MODE == 0 ? 0 : 512) + hh * 64;
    int lrow8 = ln >> 3;
    int lchunk = ((ln & 7) ^ (lrow8 & 7)) * 8;   // pre-swizzled source chunk
    // stage A (128 rows of q/k): 16 issues of 8 rows
#pragma unroll
    for (int i = 0; i < 4; i++) {
        int e = wv * 4 + i;
        size_t src = (size_t)(b * SEQN + n0 + e * 8 + lrow8) * 1024 + qoff + lchunk;
        __builtin_amdgcn_global_load_lds(AS1(qkvb + src), AS3(&As[e * 512]), 16, 0, 0);
    }
    // stage B (proj, 256 rows): 32 issues of 8 rows
#pragma unroll
    for (int i = 0; i < 8; i++) {
        int e = wv * 8 + i;
        size_t src = (size_t)(e * 8 + lrow8) * 64 + lchunk;
        __builtin_amdgcn_global_load_lds(AS1(projb + src), AS3(&Bs[e * 512]), 16, 0, 0);
    }
    __syncthreads();
    if (MODE != 1 && tid < 128) {
        float s = 0.f;
#pragma unroll
        for (int c = 0; c < 8; c++) {
            bf16x8 v = *(const bf16x8*)&As[tid * 64 + ((c ^ (tid & 7)) * 8)];
#pragma unroll
            for (int j = 0; j < 8; j++) { float f = (float)v[j]; s += f * f; }
        }
        diag_s[tid] = s * (0.5f * DN * DN);
    }
    int wr = (wv >> 1) * 64, wc = (wv & 1) * 128;
    int lr = ln & 15, kg = ln >> 4, rq = kg * 4;
    f32x4v acc[4][8] = {};
#pragma unroll
    for (int ks = 0; ks < 2; ks++) {
        int g = ks * 4 + kg;
        bf16x8 af[4], bfv[8];
#pragma unroll
        for (int m = 0; m < 4; m++) {
            int row = wr + m * 16 + lr;
            af[m] = *(const bf16x8*)&As[row * 64 + ((g ^ (row & 7)) * 8)];
        }
#pragma unroll
        for (int n = 0; n < 8; n++) {
            int row = wc + n * 16 + lr;
            bfv[n] = *(const bf16x8*)&Bs[row * 64 + ((g ^ (row & 7)) * 8)];
        }
#pragma unroll
        for (int m = 0; m < 4; m++)
#pragma unroll
            for (int n = 0; n < 8; n++)
                acc[m][n] = __builtin_amdgcn_mfma_f32_16x16x32_bf16(af[m], bfv[n], acc[m][n], 0, 0, 0);
    }
    if (MODE == 1) {
        float mx = -1e30f;
#pragma unroll
        for (int m = 0; m < 4; m++)
#pragma unroll
            for (int n = 0; n < 8; n++)
#pragma unroll
                for (int r = 0; r < 4; r++) mx = fmaxf(mx, acc[m][n][r]);
        red_s[tid] = mx * DN;
        __syncthreads();
        for (int off = 128; off > 0; off >>= 1) {
            if (tid < off) red_s[tid] = fmaxf(red_s[tid], red_s[tid + off]);
            __syncthreads();
        }
        if (tid == 0) kpart[bid] = red_s[0];
    } else if (MODE == 2) {
        float kmx = kmaxb[bh];
        __syncthreads();   // diag_s visible
#pragma unroll
        for (int m = 0; m < 4; m++) {
#pragma unroll
            for (int n = 0; n < 8; n++) {
                int col = wc + n * 16 + lr;
                bf16x4 pk;
#pragma unroll
                for (int r = 0; r < 4; r++) {
                    int row = wr + m * 16 + rq + r;
                    pk[r] = (bf16_t)(RATIO * (expf(acc[m][n][r] * DN - diag_s[row] - kmx) + EPSK));
                }
                *(bf16x4*)&outp[((size_t)bh * MF + col) * 4096 + n0 + wr + m * 16 + rq] = pk;
            }
        }
    } else {
        float pmax[4][4];
#pragma unroll
        for (int m = 0; m < 4; m++)
#pragma unroll
            for (int r = 0; r < 4; r++) {
                float mx = acc[m][0][r];
#pragma unroll
                for (int n = 1; n < 8; n++) mx = fmaxf(mx, acc[m][n][r]);
#pragma unroll
                for (int mask = 1; mask < 16; mask <<= 1)
                    mx = fmaxf(mx, __shfl_xor(mx, mask));
                pmax[m][r] = mx;
            }
        if (lr == 0) {
#pragma unroll
            for (int m = 0; m < 4; m++)
#pragma unroll
                for (int r = 0; r < 4; r++)
                    rmx_s[wv & 1][wr + m * 16 + rq + r] = pmax[m][r] * DN;
        }
        __syncthreads();
#pragma unroll
        for (int m = 0; m < 4; m++) {
#pragma unroll
            for (int r = 0; r < 4; r++) {
                int row = wr + m * 16 + rq + r;
                float rm = fmaxf(rmx_s[0][row], rmx_s[1][row]);
                float dg = diag_s[row];
                size_t obase = ((size_t)bh * SEQN + n0 + row) * MF;
#pragma unroll
                for (int n = 0; n < 8; n++) {
                    float val = RATIO * (expf(acc[m][n][r] * DN - dg - rm) + EPSK);
                    outp[obase + wc + n * 16 + lr] = (bf16_t)val;
                }
            }
        }
    }
}

__global__ __launch_bounds__(64) void kmax_reduce_kernel(const float* __restrict__ part,
                                                         float* __restrict__ kmax) {
    int bh = blockIdx.x, tid = threadIdx.x;
    float v = (tid < 32) ? part[bh * 32 + tid] : -1e30f;
#pragma unroll
    for (int off = 16; off > 0; off >>= 1) v = fmaxf(v, __shfl_down(v, off));
    if (tid == 0) kmax[bh] = v;
}

// ---------------- ksum: row sums of KPt ----------------
__global__ __launch_bounds__(256) void ksum_kernel(const bf16_t* __restrict__ KPt,
                                                   float* __restrict__ ksum) {
    int row = blockIdx.x, tid = threadIdx.x;
    const bf16_t* r = KPt + (size_t)row * 4096;
    float s = 0.f;
#pragma unroll
    for (int i = 0; i < 2; i++) {
        bf16x8 v = *(const bf16x8*)&r[tid * 16 + i * 8];
#pragma unroll
        for (int j = 0; j < 8; j++) s += (float)v[j];
    }
    __shared__ float red[256];
    red[tid] = s; __syncthreads();
    for (int off = 128; off > 0; off >>= 1) {
        if (tid < off) red[tid] += red[tid + off];
        __syncthreads();
    }
    if (tid == 0) ksum[row] = red[0];
}

// ---------------- ctx split-K GEMM: part[kc][bh][m][d] = KPt-chunk @ Vt-chunk^T ----------------
__global__ __launch_bounds__(256) void ctx_gemm(const bf16_t* __restrict__ KPt,
                                                const bf16_t* __restrict__ Vt,
                                                float* __restrict__ part) {
    int bh = blockIdx.y;
    int mtile = blockIdx.x & 1, kc = blockIdx.x >> 1;
    int m0 = mtile * 128, nb = kc * 512;
    int tid = threadIdx.x, wv = tid >> 6, ln = tid & 63;
    __shared__ __attribute__((aligned(16))) bf16_t As[128 * 64];
    __shared__ __attribute__((aligned(16))) bf16_t Bs[64 * 64];
    int lrow8 = ln >> 3;
    int lchunk = ((ln & 7) ^ (lrow8 & 7)) * 8;
    int lr = ln & 15, kg = ln >> 4, rq = kg * 4;
    int wr = wv * 32;
    f32x4v acc[2][4] = {};
    for (int kt = 0; kt < 8; kt++) {
        int noff = nb + kt * 64;
        __syncthreads();
#pragma unroll
        for (int i = 0; i < 4; i++) {
            int e = wv * 4 + i;
            __builtin_amdgcn_global_load_lds(
                AS1(KPt + ((size_t)bh * MF + m0 + e * 8 + lrow8) * 4096 + noff + lchunk),
                AS3(&As[e * 512]), 16, 0, 0);
        }
#pragma unroll
        for (int i = 0; i < 2; i++) {
            int e = wv * 2 + i;
            __builtin_amdgcn_global_load_lds(
                AS1(Vt + ((size_t)bh * 64 + e * 8 + lrow8) * 4096 + noff + lchunk),
                AS3(&Bs[e * 512]), 16, 0, 0);
        }
        __syncthreads();
#pragma unroll
        for (int ks = 0; ks < 2; ks++) {
            int g = ks * 4 + kg;
            bf16x8 af[2], bfv[4];
#pragma unroll
            for (int m = 0; m < 2; m++) {
                int row = wr + m * 16 + lr;
                af[m] = *(const bf16x8*)&As[row * 64 + ((g ^ (row & 7)) * 8)];
            }
#pragma unroll
            for (int n = 0; n < 4; n++) {
                int row = n * 16 + lr;
                bfv[n] = *(const bf16x8*)&Bs[row * 64 + ((g ^ (row & 7)) * 8)];
            }
#pragma unroll
            for (int m = 0; m < 2; m++)
#pragma unroll
                for (int n = 0; n < 4; n++)
                    acc[m][n] = __builtin_amdgcn_mfma_f32_16x16x32_bf16(af[m], bfv[n], acc[m][n], 0, 0, 0);
        }
    }
#pragma unroll
    for (int m = 0; m < 2; m++)
#pragma unroll
        for (int n = 0; n < 4; n++)
#pragma unroll
            for (int r = 0; r < 4; r++)
                part[((size_t)(kc * 16 + bh) * MF + m0 + wr + m * 16 + rq + r) * 64 + n * 16 + lr] =
                    acc[m][n][r];
}

// ---------------- ctx reduce (8 partials) -> ctx_t[bh][d][m] bf16 ----------------
__global__ __launch_bounds__(256) void ctx_reduce_kernel(const float* __restrict__ part,
                                                         bf16_t* __restrict__ ctx_t) {
    int bh = blockIdx.x;
    for (int it = 0; it < 64; it++) {
        int idx = it * 256 + threadIdx.x;
        int m = idx >> 6, d = idx & 63;
        float s = 0.f;
#pragma unroll
        for (int kc = 0; kc < 8; kc++)
            s += part[(size_t)(kc * 16 + bh) * 16384 + idx];
        ctx_t[((size_t)bh * 64 + d) * MF + m] = (bf16_t)s;
    }
}

// ---------------- dinv[bh][n] = 1 / (QP[n,:] . ksum[bh,:]) ----------------
__global__ __launch_bounds__(256) void dinv_kernel(const bf16_t* __restrict__ QP,
                                                   const float* __restrict__ ksum,
                                                   float* __restrict__ dinv) {
    int bid = blockIdx.x, tid = threadIdx.x;
    int bh = bid >> 4;
    __shared__ float ks[256];
    ks[tid] = ksum[bh * MF + tid];
    __syncthreads();
    size_t row = (size_t)bid * 256 + tid;
    const bf16_t* q = QP + row * MF;
    float s = 0.f;
#pragma unroll
    for (int i = 0; i < 32; i++) {
        bf16x8 v = *(const bf16x8*)&q[i * 8];
#pragma unroll
        for (int j = 0; j < 8; j++) s += (float)v[j] * ks[i * 8 + j];
    }
    dinv[row] = 1.0f / s;
}

// ---------------- out GEMM: abuf[n][h*64+d] = (QP @ ctx_t^T)[n][d] * dinv[n] ----------------
__global__ __launch_bounds__(256) void out_gemm(const bf16_t* __restrict__ QP,
                                                const bf16_t* __restrict__ ctx_t,
                                                const float* __restrict__ dinv,
                                                bf16_t* __restrict__ abuf) {
    int bh = blockIdx.y, ntile = blockIdx.x;
    int b = bh >> 3, hh = bh & 7;
    int n0 = ntile * 128;
    int tid = threadIdx.x, wv = tid >> 6, ln = tid & 63;
    __shared__ __attribute__((aligned(16))) bf16_t As[128 * 64];
    __shared__ __attribute__((aligned(16))) bf16_t Bs[64 * 64];
    int lrow8 = ln >> 3;
    int lchunk = ((ln & 7) ^ (lrow8 & 7)) * 8;
    int lr = ln & 15, kg = ln >> 4, rq = kg * 4;
    int wr = wv * 32;
    f32x4v acc[2][4] = {};
    for (int kt = 0; kt < 4; kt++) {
        int koff = kt * 64;
        __syncthreads();
#pragma unroll
        for (int i = 0; i < 4; i++) {
            int e = wv * 4 + i;
            __builtin_amdgcn_global_load_lds(
                AS1(QP + ((size_t)bh * SEQN + n0 + e * 8 + lrow8) * MF + koff + lchunk),
                AS3(&As[e * 512]), 16, 0, 0);
        }
#pragma unroll
        for (int i = 0; i < 2; i++) {
            int e = wv * 2 + i;
            __builtin_amdgcn_global_load_lds(
                AS1(ctx_t + ((size_t)bh * 64 + e * 8 + lrow8) * MF + koff + lchunk),
                AS3(&Bs[e * 512]), 16, 0, 0);
        }
        __syncthreads();
#pragma unroll
        for (int ks = 0; ks < 2; ks++) {
            int g = ks * 4 + kg;
            bf16x8 af[2], bfv[4];
#pragma unroll
            for (int m = 0; m < 2; m++) {
                int row = wr + m * 16 + lr;
                af[m] = *(const bf16x8*)&As[row * 64 + ((g ^ (row & 7)) * 8)];
            }
#pragma unroll
            for (int n = 0; n < 4; n++) {
                int row = n * 16 + lr;
                bfv[n] = *(const bf16x8*)&Bs[row * 64 + ((g ^ (row & 7)) * 8)];
            }
#pragma unroll
            for (int m = 0; m < 2; m++)
#pragma unroll
                for (int n = 0; n < 4; n++)
                    acc[m][n] = __builtin_amdgcn_mfma_f32_16x16x32_bf16(af[m], bfv[n], acc[m][n], 0, 0, 0);
        }
    }
#pragma unroll
    for (int m = 0; m < 2; m++) {
#pragma unroll
        for (int r = 0; r < 4; r++) {
            int row = n0 + wr + m * 16 + rq + r;
            float di = dinv[(size_t)bh * SEQN + row];
#pragma unroll
            for (int n = 0; n < 4; n++)
                abuf[((size_t)b * SEQN + row) * DMODEL + hh * 64 + n * 16 + lr] =
                    (bf16_t)(acc[m][n][r] * di);
        }
    }
}

extern "C" void kernel_launch(void* const* d_in, const int* in_sizes, int n_in,
                              void* d_out, int out_size, void* d_ws, size_t ws_size,
                              hipStream_t stream) {
    const float* x     = (const float*)d_in[0];
    const float* proj  = (const float*)d_in[1];
    const float* ln1_g = (const float*)d_in[2];
    const float* ln1_b = (const float*)d_in[3];
    const float* Wqkv  = (const float*)d_in[4];
    const float* bqkv  = (const float*)d_in[5];
    const float* Wo    = (const float*)d_in[6];
    const float* bo    = (const float*)d_in[7];
    const float* ln2_g = (const float*)d_in[8];
    const float* ln2_b = (const float*)d_in[9];
    const float* Wff1  = (const float*)d_in[10];
    const float* bff1  = (const float*)d_in[11];
    const float* Wff2  = (const float*)d_in[12];
    const float* bff2  = (const float*)d_in[13];

    float* h = (float*)d_out;
    char* ws = (char*)d_ws;
    // Region 0: KPt (32Mi). ybf aliases its first 8Mi (dead before KPt written; ln2 after ctx).
    bf16_t* KPt   = (bf16_t*)(ws);
    bf16_t* ybf   = (bf16_t*)(ws);
    // Region 1: qkvb Q+K [8192][1024] (16Mi). abuf aliases [0,8Mi); ctx_part aliases [8Mi,16Mi).
    bf16_t* qkvb  = (bf16_t*)(ws + 33554432);
    bf16_t* abufb = (bf16_t*)(ws + 33554432);
    float*  ctx_part = (float*)(ws + 33554432 + 8388608);
    // Region 2: QP (32Mi). ffmid aliases (dead after out_gemm/dinv).
    bf16_t* QP    = (bf16_t*)(ws + 50331648);
    bf16_t* ffmidb= (bf16_t*)(ws + 50331648);
    // Region 3: Vt (8Mi)
    bf16_t* Vt    = (bf16_t*)(ws + 83886080);
    // Region 4: weights + small
    bf16_t* wq_t  = (bf16_t*)(ws + 92274688);   // 1536*512*2
    bf16_t* wo_t  = (bf16_t*)(ws + 93847552);   // 512*512*2
    bf16_t* w1_t  = (bf16_t*)(ws + 94371840);   // 2048*512*2
    bf16_t* w2_t  = (bf16_t*)(ws + 96468992);   // 512*2048*2
    bf16_t* projb = (bf16_t*)(ws + 98566144);   // 4*256*64*2
    bf16_t* ctx_t = (bf16_t*)(ws + 98697216);   // 16*64*256*2
    float*  ksumb = (float*)(ws + 99221504);    // 4096*4
    float*  dinvb = (float*)(ws + 99237888);    // 65536*4
    float*  kpart = (float*)(ws + 99500032);    // 512*4
    float*  kmaxb = (float*)(ws + 99502080);    // 16*4

    hipMemcpyAsync(h, x, (size_t)NROWS * DMODEL * sizeof(float),
                   hipMemcpyDeviceToDevice, stream);
    pconv_kernel<<<64, 256, 0, stream>>>(proj, projb);

    for (int i = 0; i < DEPTH; i++) {
        const bf16_t* pj = projb + (size_t)i * MF * DH;
        wconv_kernel<<<dim3(1536 / 32, 512 / 32), 256, 0, stream>>>(
            Wqkv + (size_t)i * DMODEL * 1536, wq_t, 512, 1536);
        wconv_kernel<<<dim3(512 / 32, 512 / 32), 256, 0, stream>>>(
            Wo + (size_t)i * DMODEL * DMODEL, wo_t, 512, 512);
        wconv_kernel<<<dim3(2048 / 32, 512 / 32), 256, 0, stream>>>(
            Wff1 + (size_t)i * DMODEL * FFD, w1_t, 512, 2048);
        wconv_kernel<<<dim3(512 / 32, 2048 / 32), 256, 0, stream>>>(
            Wff2 + (size_t)i * FFD * DMODEL, w2_t, 2048, 512);

        ln_kernel<<<NROWS, 256, 0, stream>>>(h, ln1_g + i * DMODEL, ln1_b + i * DMODEL, ybf);
        gemm_mfma<0, 0, 0, 0, 1><<<dim3(1536 / 128, NROWS / 128), 256, 0, stream>>>(
            ybf, wq_t, bqkv + i * 1536, nullptr, qkvb, Vt, 1536, 512);
        feat_kernel<1><<<512, 256, 0, stream>>>(qkvb, pj, nullptr, nullptr, kpart);
        kmax_reduce_kernel<<<16, 64, 0, stream>>>(kpart, kmaxb);
        feat_kernel<2><<<512, 256, 0, stream>>>(qkvb, pj, kmaxb, KPt, nullptr);
        ksum_kernel<<<4096, 256, 0, stream>>>(KPt, ksumb);
        feat_kernel<0><<<512, 256, 0, stream>>>(qkvb, pj, nullptr, QP, nullptr);
        ctx_gemm<<<dim3(16, 16), 256, 0, stream>>>(KPt, Vt, ctx_part);
        ctx_reduce_kernel<<<16, 256, 0, stream>>>(ctx_part, ctx_t);
        dinv_kernel<<<256, 256, 0, stream>>>(QP, ksumb, dinvb);
        out_gemm<<<dim3(32, 16), 256, 0, stream>>>(QP, ctx_t, dinvb, abufb);
        gemm_mfma<0, 1, 1, 0, 0><<<dim3(512 / 128, NROWS / 128), 256, 0, stream>>>(
            abufb, wo_t, bo + i * DMODEL, h, nullptr, nullptr, 512, 512);

        ln_kernel<<<NROWS, 256, 0, stream>>>(h, ln2_g + i * DMODEL, ln2_b + i * DMODEL, ybf);
        gemm_mfma<1, 0, 0, 1, 0><<<dim3(2048 / 128, NROWS / 128), 256, 0, stream>>>(
            ybf, w1_t, bff1 + i * FFD, nullptr, ffmidb, nullptr, 2048, 512);
        gemm_mfma<0, 1, 1, 0, 0><<<dim3(512 / 128, NROWS / 128), 256, 0, stream>>>(
            ffmidb, w2_t, bff2 + i * DMODEL, h, nullptr, nullptr, 512, 2048);
    }
}

// Round 4
// 1008.464 us; speedup vs baseline: 6.0068x; 1.1566x over previous
//
#include <hip/hip_runtime.h>
#include <math.h>

#define DEPTH 4
#define DMODEL 512
#define DH 64
#define MF 256
#define FFD 2048
#define SEQN 4096
#define NROWS 8192

typedef __bf16 bf16_t;
typedef bf16_t bf16x8 __attribute__((ext_vector_type(8)));
typedef bf16_t bf16x4 __attribute__((ext_vector_type(4)));
typedef float f32x4v __attribute__((ext_vector_type(4)));

static constexpr float DN = 0.35355339059327373f;   // 64^-0.25
static constexpr float RATIO = 0.0625f;             // 256^-0.5
static constexpr float EPSK = 1e-4f;

__device__ __forceinline__ float gelu_exact(float x) {
    return 0.5f * x * (1.0f + erff(x * 0.70710678118654752f));
}

#define AS1(p) ((const __attribute__((address_space(1))) void*)(p))
#define AS3(p) ((__attribute__((address_space(3))) void*)(p))

// ---------------- LayerNorm -> bf16 ----------------
__global__ __launch_bounds__(256) void ln_kernel(const float* __restrict__ h,
                                                 const float* __restrict__ g,
                                                 const float* __restrict__ b,
                                                 bf16_t* __restrict__ y) {
    int row = blockIdx.x, tid = threadIdx.x;
    const float* hr = h + (size_t)row * DMODEL;
    float v0 = hr[tid], v1 = hr[tid + 256];
    __shared__ float s_sum[256], s_sq[256];
    s_sum[tid] = v0 + v1;
    s_sq[tid] = v0 * v0 + v1 * v1;
    __syncthreads();
    for (int off = 128; off > 0; off >>= 1) {
        if (tid < off) { s_sum[tid] += s_sum[tid + off]; s_sq[tid] += s_sq[tid + off]; }
        __syncthreads();
    }
    float mu = s_sum[0] * (1.0f / DMODEL);
    float var = s_sq[0] * (1.0f / DMODEL) - mu * mu;
    float rstd = rsqrtf(var + 1e-5f);
    bf16_t* yr = y + (size_t)row * DMODEL;
    yr[tid]       = (bf16_t)((v0 - mu) * rstd * g[tid] + b[tid]);
    yr[tid + 256] = (bf16_t)((v1 - mu) * rstd * g[tid + 256] + b[tid + 256]);
}

// ---------------- weight transpose + bf16 convert: Wt[N][K] = (bf16)W[K][N] ----------------
__global__ __launch_bounds__(256) void wconv_kernel(const float* __restrict__ W,
                                                    bf16_t* __restrict__ Wt, int K, int N) {
    __shared__ float t[32][33];
    int n0 = blockIdx.x * 32, k0 = blockIdx.y * 32;
    int tx = threadIdx.x & 31, ty = threadIdx.x >> 5;
#pragma unroll
    for (int i = 0; i < 32; i += 8)
        t[ty + i][tx] = W[(size_t)(k0 + ty + i) * N + n0 + tx];
    __syncthreads();
#pragma unroll
    for (int i = 0; i < 32; i += 8)
        Wt[(size_t)(n0 + ty + i) * K + k0 + tx] = (bf16_t)t[tx][ty + i];
}

// ---------------- proj -> bf16 (no transpose; proj is [m][dh] = [N][K]) ----------------
__global__ __launch_bounds__(256) void pconv_kernel(const float* __restrict__ proj,
                                                    bf16_t* __restrict__ projb) {
    int i = (blockIdx.x * 256 + threadIdx.x) * 4;
    float4 v = *(const float4*)(proj + i);
    bf16x4 o;
    o[0] = (bf16_t)v.x; o[1] = (bf16_t)v.y; o[2] = (bf16_t)v.z; o[3] = (bf16_t)v.w;
    *(bf16x4*)(projb + i) = o;
}

// ---------------- MFMA GEMM: C[M,N] = act(A[M,K] @ Bt[N,K]^T + bias) ----------------
// BMxBN tile, BK=32, 8 waves (WROWSxWCOLS), double-buffered LDS + prefetch (2-phase),
// XOR chunk swizzle (chunk ^ row&3) on both gload-source and ds_read.
// QKVE: qkv-special epilogue (Q,K -> qkvb stride 1024; V -> Vt[bh*64+d][n] transposed)
template <int BM, int BN, int WROWS, int WCOLS, int ACT, int RES, int WF, int WB, int QKVE>
__global__ __launch_bounds__(512) void gemm_mfma(const bf16_t* __restrict__ A,
                                                 const bf16_t* __restrict__ Bt,
                                                 const float* __restrict__ bias,
                                                 float* __restrict__ Cf,
                                                 bf16_t* __restrict__ Cb,
                                                 bf16_t* __restrict__ Vt,
                                                 int N, int K) {
    constexpr int MR = BM / WROWS / 16;
    constexpr int NR = BN / WCOLS / 16;
    __shared__ __attribute__((aligned(16))) bf16_t As[2][BM * 32];
    __shared__ __attribute__((aligned(16))) bf16_t Bs[2][BN * 32];
    int tid = threadIdx.x;
    int wv = tid >> 6, ln = tid & 63;
    int m0 = blockIdx.y * BM, n0 = blockIdx.x * BN;
    int wr = (wv / WCOLS) * (MR * 16), wc = (wv % WCOLS) * (NR * 16);
    int lr = ln & 15, kq8 = ln >> 4;
    int arow = tid >> 2;
    int achunk = (tid & 3) ^ (arow & 3);   // inverse-swizzled source chunk
    const bf16_t* asrc0 = A + (size_t)(m0 + arow) * K + achunk * 8;
    const bf16_t* bsrc0 = Bt + (size_t)(n0 + arow) * K + achunk * 8;   // used if tid < BN*4
    f32x4v acc[MR][NR] = {};
    int nsteps = K / 32;
    // prologue: stage k-tile 0 into buf 0
    __builtin_amdgcn_global_load_lds(AS1(asrc0), AS3(&As[0][tid * 8]), 16, 0, 0);
    if (tid < BN * 4)
        __builtin_amdgcn_global_load_lds(AS1(bsrc0), AS3(&Bs[0][tid * 8]), 16, 0, 0);
    __syncthreads();
    for (int t = 0; t < nsteps; ++t) {
        int cur = t & 1;
        if (t + 1 < nsteps) {   // prefetch next k-tile into other buffer
            int k1 = (t + 1) * 32;
            __builtin_amdgcn_global_load_lds(AS1(asrc0 + k1), AS3(&As[cur ^ 1][tid * 8]), 16, 0, 0);
            if (tid < BN * 4)
                __builtin_amdgcn_global_load_lds(AS1(bsrc0 + k1), AS3(&Bs[cur ^ 1][tid * 8]), 16, 0, 0);
        }
        bf16x8 af[MR], bfr[NR];
#pragma unroll
        for (int m = 0; m < MR; m++) {
            int row = wr + m * 16 + lr;
            af[m] = *(const bf16x8*)&As[cur][row * 32 + ((kq8 ^ (row & 3)) * 8)];
        }
#pragma unroll
        for (int n = 0; n < NR; n++) {
            int row = wc + n * 16 + lr;
            bfr[n] = *(const bf16x8*)&Bs[cur][row * 32 + ((kq8 ^ (row & 3)) * 8)];
        }
#pragma unroll
        for (int m = 0; m < MR; m++)
#pragma unroll
            for (int n = 0; n < NR; n++)
                acc[m][n] = __builtin_amdgcn_mfma_f32_16x16x32_bf16(af[m], bfr[n], acc[m][n], 0, 0, 0);
        if (t + 1 < nsteps) __syncthreads();
    }
    int rq = (ln >> 4) * 4;
#pragma unroll
    for (int n = 0; n < NR; n++) {
        int col = n0 + wc + n * 16 + lr;
        float bcol = bias[col];
#pragma unroll
        for (int m = 0; m < MR; m++) {
#pragma unroll
            for (int r = 0; r < 4; r++) {
                int row = m0 + wr + m * 16 + rq + r;
                float v = acc[m][n][r] + bcol;
                if (ACT == 1) v = gelu_exact(v);
                if (QKVE) {
                    int bb = row >> 12, nn = row & 4095;
                    if (col < 1024) {
                        Cb[(size_t)row * 1024 + col] = (bf16_t)v;
                    } else {
                        int hh2 = (col >> 6) & 7, dd2 = col & 63;
                        Vt[(((size_t)bb * 8 + hh2) * 64 + dd2) * 4096 + nn] = (bf16_t)v;
                    }
                } else {
                    size_t idx = (size_t)row * N + col;
                    if (RES) Cf[idx] += v;
                    else if (WF) Cf[idx] = v;
                    if (WB) Cb[idx] = (bf16_t)v;
                }
            }
        }
    }
}

// ---------------- FAVOR+ feature GEMM: dd[128n x 256m] per block, K=64 ----------------
// MODE 0 = Q (rowmax+exp -> QP[bh][n][m] bf16)
// MODE 1 = K max pass (block max of dd -> kpart)
// MODE 2 = K write pass (exp with kmx -> KPt[bh][m][n] bf16, transposed)
template <int MODE>
__global__ __launch_bounds__(256) void feat_kernel(const bf16_t* __restrict__ qkvb,
                                                   const bf16_t* __restrict__ projb,
                                                   const float* __restrict__ kmaxb,
                                                   bf16_t* __restrict__ outp,
                                                   float* __restrict__ kpart) {
    int bid = blockIdx.x;
    int bh = bid >> 5, tile = bid & 31;
    int b = bh >> 3, hh = bh & 7;
    int tid = threadIdx.x, wv = tid >> 6, ln = tid & 63;
    __shared__ __attribute__((aligned(16))) bf16_t As[128 * 64];
    __shared__ __attribute__((aligned(16))) bf16_t Bs[256 * 64];
    __shared__ float diag_s[128];
    __shared__ float rmx_s[2][128];
    __shared__ float red_s[256];
    int n0 = tile * 128;
    int qoff = (MODE == 0 ? 0 : 512) + hh * 64;
    int lrow8 = ln >> 3;
    int lchunk = ((ln & 7) ^ (lrow8 & 7)) * 8;   // pre-swizzled source chunk
#pragma unroll
    for (int i = 0; i < 4; i++) {
        int e = wv * 4 + i;
        size_t src = (size_t)(b * SEQN + n0 + e * 8 + lrow8) * 1024 + qoff + lchunk;
        __builtin_amdgcn_global_load_lds(AS1(qkvb + src), AS3(&As[e * 512]), 16, 0, 0);
    }
#pragma unroll
    for (int i = 0; i < 8; i++) {
        int e = wv * 8 + i;
        size_t src = (size_t)(e * 8 + lrow8) * 64 + lchunk;
        __builtin_amdgcn_global_load_lds(AS1(projb + src), AS3(&Bs[e * 512]), 16, 0, 0);
    }
    __syncthreads();
    if (MODE != 1 && tid < 128) {
        float s = 0.f;
#pragma unroll
        for (int c = 0; c < 8; c++) {
            bf16x8 v = *(const bf16x8*)&As[tid * 64 + ((c ^ (tid & 7)) * 8)];
#pragma unroll
            for (int j = 0; j < 8; j++) { float f = (float)v[j]; s += f * f; }
        }
        diag_s[tid] = s * (0.5f * DN * DN);
    }
    int wr = (wv >> 1) * 64, wc = (wv & 1) * 128;
    int lr = ln & 15, kg = ln >> 4, rq = kg * 4;
    f32x4v acc[4][8] = {};
#pragma unroll
    for (int ks = 0; ks < 2; ks++) {
        int g = ks * 4 + kg;
        bf16x8 af[4], bfv[8];
#pragma unroll
        for (int m = 0; m < 4; m++) {
            int row = wr + m * 16 + lr;
            af[m] = *(const bf16x8*)&As[row * 64 + ((g ^ (row & 7)) * 8)];
        }
#pragma unroll
        for (int n = 0; n < 8; n++) {
            int row = wc + n * 16 + lr;
            bfv[n] = *(const bf16x8*)&Bs[row * 64 + ((g ^ (row & 7)) * 8)];
        }
#pragma unroll
        for (int m = 0; m < 4; m++)
#pragma unroll
            for (int n = 0; n < 8; n++)
                acc[m][n] = __builtin_amdgcn_mfma_f32_16x16x32_bf16(af[m], bfv[n], acc[m][n], 0, 0, 0);
    }
    if (MODE == 1) {
        float mx = -1e30f;
#pragma unroll
        for (int m = 0; m < 4; m++)
#pragma unroll
            for (int n = 0; n < 8; n++)
#pragma unroll
                for (int r = 0; r < 4; r++) mx = fmaxf(mx, acc[m][n][r]);
        red_s[tid] = mx * DN;
        __syncthreads();
        for (int off = 128; off > 0; off >>= 1) {
            if (tid < off) red_s[tid] = fmaxf(red_s[tid], red_s[tid + off]);
            __syncthreads();
        }
        if (tid == 0) kpart[bid] = red_s[0];
    } else if (MODE == 2) {
        float kmx = kmaxb[bh];
        __syncthreads();   // diag_s visible
#pragma unroll
        for (int m = 0; m < 4; m++) {
#pragma unroll
            for (int n = 0; n < 8; n++) {
                int col = wc + n * 16 + lr;
                bf16x4 pk;
#pragma unroll
                for (int r = 0; r < 4; r++) {
                    int row = wr + m * 16 + rq + r;
                    pk[r] = (bf16_t)(RATIO * (expf(acc[m][n][r] * DN - diag_s[row] - kmx) + EPSK));
                }
                *(bf16x4*)&outp[((size_t)bh * MF + col) * 4096 + n0 + wr + m * 16 + rq] = pk;
            }
        }
    } else {
        float pmax[4][4];
#pragma unroll
        for (int m = 0; m < 4; m++)
#pragma unroll
            for (int r = 0; r < 4; r++) {
                float mx = acc[m][0][r];
#pragma unroll
                for (int n = 1; n < 8; n++) mx = fmaxf(mx, acc[m][n][r]);
#pragma unroll
                for (int mask = 1; mask < 16; mask <<= 1)
                    mx = fmaxf(mx, __shfl_xor(mx, mask));
                pmax[m][r] = mx;
            }
        if (lr == 0) {
#pragma unroll
            for (int m = 0; m < 4; m++)
#pragma unroll
                for (int r = 0; r < 4; r++)
                    rmx_s[wv & 1][wr + m * 16 + rq + r] = pmax[m][r] * DN;
        }
        __syncthreads();
#pragma unroll
        for (int m = 0; m < 4; m++) {
#pragma unroll
            for (int r = 0; r < 4; r++) {
                int row = wr + m * 16 + rq + r;
                float rm = fmaxf(rmx_s[0][row], rmx_s[1][row]);
                float dg = diag_s[row];
                size_t obase = ((size_t)bh * SEQN + n0 + row) * MF;
#pragma unroll
                for (int n = 0; n < 8; n++) {
                    float val = RATIO * (expf(acc[m][n][r] * DN - dg - rm) + EPSK);
                    outp[obase + wc + n * 16 + lr] = (bf16_t)val;
                }
            }
        }
    }
}

__global__ __launch_bounds__(64) void kmax_reduce_kernel(const float* __restrict__ part,
                                                         float* __restrict__ kmax) {
    int bh = blockIdx.x, tid = threadIdx.x;
    float v = (tid < 32) ? part[bh * 32 + tid] : -1e30f;
#pragma unroll
    for (int off = 16; off > 0; off >>= 1) v = fmaxf(v, __shfl_down(v, off));
    if (tid == 0) kmax[bh] = v;
}

// ---------------- ksum: row sums of KPt ----------------
__global__ __launch_bounds__(256) void ksum_kernel(const bf16_t* __restrict__ KPt,
                                                   float* __restrict__ ksum) {
    int row = blockIdx.x, tid = threadIdx.x;
    const bf16_t* r = KPt + (size_t)row * 4096;
    float s = 0.f;
#pragma unroll
    for (int i = 0; i < 2; i++) {
        bf16x8 v = *(const bf16x8*)&r[tid * 16 + i * 8];
#pragma unroll
        for (int j = 0; j < 8; j++) s += (float)v[j];
    }
    __shared__ float red[256];
    red[tid] = s; __syncthreads();
    for (int off = 128; off > 0; off >>= 1) {
        if (tid < off) red[tid] += red[tid + off];
        __syncthreads();
    }
    if (tid == 0) ksum[row] = red[0];
}

// ---------------- ctx split-K GEMM: part[kc][bh][m][d] = KPt-chunk @ Vt-chunk^T ----------------
__global__ __launch_bounds__(256) void ctx_gemm(const bf16_t* __restrict__ KPt,
                                                const bf16_t* __restrict__ Vt,
                                                float* __restrict__ part) {
    int bh = blockIdx.y;
    int mtile = blockIdx.x & 1, kc = blockIdx.x >> 1;
    int m0 = mtile * 128, nb = kc * 512;
    int tid = threadIdx.x, wv = tid >> 6, ln = tid & 63;
    __shared__ __attribute__((aligned(16))) bf16_t As[128 * 64];
    __shared__ __attribute__((aligned(16))) bf16_t Bs[64 * 64];
    int lrow8 = ln >> 3;
    int lchunk = ((ln & 7) ^ (lrow8 & 7)) * 8;
    int lr = ln & 15, kg = ln >> 4, rq = kg * 4;
    int wr = wv * 32;
    f32x4v acc[2][4] = {};
    for (int kt = 0; kt < 8; kt++) {
        int noff = nb + kt * 64;
        __syncthreads();
#pragma unroll
        for (int i = 0; i < 4; i++) {
            int e = wv * 4 + i;
            __builtin_amdgcn_global_load_lds(
                AS1(KPt + ((size_t)bh * MF + m0 + e * 8 + lrow8) * 4096 + noff + lchunk),
                AS3(&As[e * 512]), 16, 0, 0);
        }
#pragma unroll
        for (int i = 0; i < 2; i++) {
            int e = wv * 2 + i;
            __builtin_amdgcn_global_load_lds(
                AS1(Vt + ((size_t)bh * 64 + e * 8 + lrow8) * 4096 + noff + lchunk),
                AS3(&Bs[e * 512]), 16, 0, 0);
        }
        __syncthreads();
#pragma unroll
        for (int ks = 0; ks < 2; ks++) {
            int g = ks * 4 + kg;
            bf16x8 af[2], bfv[4];
#pragma unroll
            for (int m = 0; m < 2; m++) {
                int row = wr + m * 16 + lr;
                af[m] = *(const bf16x8*)&As[row * 64 + ((g ^ (row & 7)) * 8)];
            }
#pragma unroll
            for (int n = 0; n < 4; n++) {
                int row = n * 16 + lr;
                bfv[n] = *(const bf16x8*)&Bs[row * 64 + ((g ^ (row & 7)) * 8)];
            }
#pragma unroll
            for (int m = 0; m < 2; m++)
#pragma unroll
                for (int n = 0; n < 4; n++)
                    acc[m][n] = __builtin_amdgcn_mfma_f32_16x16x32_bf16(af[m], bfv[n], acc[m][n], 0, 0, 0);
        }
    }
#pragma unroll
    for (int m = 0; m < 2; m++)
#pragma unroll
        for (int n = 0; n < 4; n++)
#pragma unroll
            for (int r = 0; r < 4; r++)
                part[((size_t)(kc * 16 + bh) * MF + m0 + wr + m * 16 + rq + r) * 64 + n * 16 + lr] =
                    acc[m][n][r];
}

// ---------------- ctx reduce (8 partials) -> ctx_t[bh][d][m] bf16 ----------------
__global__ __launch_bounds__(256) void ctx_reduce_kernel(const float* __restrict__ part,
                                                         bf16_t* __restrict__ ctx_t) {
    int bh = blockIdx.x;
    for (int it = 0; it < 64; it++) {
        int idx = it * 256 + threadIdx.x;
        int m = idx >> 6, d = idx & 63;
        float s = 0.f;
#pragma unroll
        for (int kc = 0; kc < 8; kc++)
            s += part[(size_t)(kc * 16 + bh) * 16384 + idx];
        ctx_t[((size_t)bh * 64 + d) * MF + m] = (bf16_t)s;
    }
}

// ---------------- dinv[bh][n] = 1 / (QP[n,:] . ksum[bh,:]) ----------------
__global__ __launch_bounds__(256) void dinv_kernel(const bf16_t* __restrict__ QP,
                                                   const float* __restrict__ ksum,
                                                   float* __restrict__ dinv) {
    int bid = blockIdx.x, tid = threadIdx.x;
    int bh = bid >> 4;
    __shared__ float ks[256];
    ks[tid] = ksum[bh * MF + tid];
    __syncthreads();
    size_t row = (size_t)bid * 256 + tid;
    const bf16_t* q = QP + row * MF;
    float s = 0.f;
#pragma unroll
    for (int i = 0; i < 32; i++) {
        bf16x8 v = *(const bf16x8*)&q[i * 8];
#pragma unroll
        for (int j = 0; j < 8; j++) s += (float)v[j] * ks[i * 8 + j];
    }
    dinv[row] = 1.0f / s;
}

// ---------------- out GEMM: abuf[n][h*64+d] = (QP @ ctx_t^T)[n][d] * dinv[n] ----------------
__global__ __launch_bounds__(256) void out_gemm(const bf16_t* __restrict__ QP,
                                                const bf16_t* __restrict__ ctx_t,
                                                const float* __restrict__ dinv,
                                                bf16_t* __restrict__ abuf) {
    int bh = blockIdx.y, ntile = blockIdx.x;
    int b = bh >> 3, hh = bh & 7;
    int n0 = ntile * 128;
    int tid = threadIdx.x, wv = tid >> 6, ln = tid & 63;
    __shared__ __attribute__((aligned(16))) bf16_t As[128 * 64];
    __shared__ __attribute__((aligned(16))) bf16_t Bs[64 * 64];
    int lrow8 = ln >> 3;
    int lchunk = ((ln & 7) ^ (lrow8 & 7)) * 8;
    int lr = ln & 15, kg = ln >> 4, rq = kg * 4;
    int wr = wv * 32;
    f32x4v acc[2][4] = {};
    for (int kt = 0; kt < 4; kt++) {
        int koff = kt * 64;
        __syncthreads();
#pragma unroll
        for (int i = 0; i < 4; i++) {
            int e = wv * 4 + i;
            __builtin_amdgcn_global_load_lds(
                AS1(QP + ((size_t)bh * SEQN + n0 + e * 8 + lrow8) * MF + koff + lchunk),
                AS3(&As[e * 512]), 16, 0, 0);
        }
#pragma unroll
        for (int i = 0; i < 2; i++) {
            int e = wv * 2 + i;
            __builtin_amdgcn_global_load_lds(
                AS1(ctx_t + ((size_t)bh * 64 + e * 8 + lrow8) * MF + koff + lchunk),
                AS3(&Bs[e * 512]), 16, 0, 0);
        }
        __syncthreads();
#pragma unroll
        for (int ks = 0; ks < 2; ks++) {
            int g = ks * 4 + kg;
            bf16x8 af[2], bfv[4];
#pragma unroll
            for (int m = 0; m < 2; m++) {
                int row = wr + m * 16 + lr;
                af[m] = *(const bf16x8*)&As[row * 64 + ((g ^ (row & 7)) * 8)];
            }
#pragma unroll
            for (int n = 0; n < 4; n++) {
                int row = n * 16 + lr;
                bfv[n] = *(const bf16x8*)&Bs[row * 64 + ((g ^ (row & 7)) * 8)];
            }
#pragma unroll
            for (int m = 0; m < 2; m++)
#pragma unroll
                for (int n = 0; n < 4; n++)
                    acc[m][n] = __builtin_amdgcn_mfma_f32_16x16x32_bf16(af[m], bfv[n], acc[m][n], 0, 0, 0);
        }
    }
#pragma unroll
    for (int m = 0; m < 2; m++) {
#pragma unroll
        for (int r = 0; r < 4; r++) {
            int row = n0 + wr + m * 16 + rq + r;
            float di = dinv[(size_t)bh * SEQN + row];
#pragma unroll
            for (int n = 0; n < 4; n++)
                abuf[((size_t)b * SEQN + row) * DMODEL + hh * 64 + n * 16 + lr] =
                    (bf16_t)(acc[m][n][r] * di);
        }
    }
}

extern "C" void kernel_launch(void* const* d_in, const int* in_sizes, int n_in,
                              void* d_out, int out_size, void* d_ws, size_t ws_size,
                              hipStream_t stream) {
    const float* x     = (const float*)d_in[0];
    const float* proj  = (const float*)d_in[1];
    const float* ln1_g = (const float*)d_in[2];
    const float* ln1_b = (const float*)d_in[3];
    const float* Wqkv  = (const float*)d_in[4];
    const float* bqkv  = (const float*)d_in[5];
    const float* Wo    = (const float*)d_in[6];
    const float* bo    = (const float*)d_in[7];
    const float* ln2_g = (const float*)d_in[8];
    const float* ln2_b = (const float*)d_in[9];
    const float* Wff1  = (const float*)d_in[10];
    const float* bff1  = (const float*)d_in[11];
    const float* Wff2  = (const float*)d_in[12];
    const float* bff2  = (const float*)d_in[13];

    float* h = (float*)d_out;
    char* ws = (char*)d_ws;
    // Region 0: KPt (32Mi). ybf aliases its first 8Mi (dead before KPt written; ln2 after ctx).
    bf16_t* KPt   = (bf16_t*)(ws);
    bf16_t* ybf   = (bf16_t*)(ws);
    // Region 1: qkvb Q+K [8192][1024] (16Mi). abuf aliases [0,8Mi); ctx_part aliases [8Mi,16Mi).
    bf16_t* qkvb  = (bf16_t*)(ws + 33554432);
    bf16_t* abufb = (bf16_t*)(ws + 33554432);
    float*  ctx_part = (float*)(ws + 33554432 + 8388608);
    // Region 2: QP (32Mi). ffmid aliases (dead after out_gemm/dinv).
    bf16_t* QP    = (bf16_t*)(ws + 50331648);
    bf16_t* ffmidb= (bf16_t*)(ws + 50331648);
    // Region 3: Vt (8Mi)
    bf16_t* Vt    = (bf16_t*)(ws + 83886080);
    // Region 4: weights + small
    bf16_t* wq_t  = (bf16_t*)(ws + 92274688);   // 1536*512*2
    bf16_t* wo_t  = (bf16_t*)(ws + 93847552);   // 512*512*2
    bf16_t* w1_t  = (bf16_t*)(ws + 94371840);   // 2048*512*2
    bf16_t* w2_t  = (bf16_t*)(ws + 96468992);   // 512*2048*2
    bf16_t* projb = (bf16_t*)(ws + 98566144);   // 4*256*64*2
    bf16_t* ctx_t = (bf16_t*)(ws + 98697216);   // 16*64*256*2
    float*  ksumb = (float*)(ws + 99221504);    // 4096*4
    float*  dinvb = (float*)(ws + 99237888);    // 65536*4
    float*  kpart = (float*)(ws + 99500032);    // 512*4
    float*  kmaxb = (float*)(ws + 99502080);    // 16*4

    hipMemcpyAsync(h, x, (size_t)NROWS * DMODEL * sizeof(float),
                   hipMemcpyDeviceToDevice, stream);
    pconv_kernel<<<64, 256, 0, stream>>>(proj, projb);

    for (int i = 0; i < DEPTH; i++) {
        const bf16_t* pj = projb + (size_t)i * MF * DH;
        wconv_kernel<<<dim3(1536 / 32, 512 / 32), 256, 0, stream>>>(
            Wqkv + (size_t)i * DMODEL * 1536, wq_t, 512, 1536);
        wconv_kernel<<<dim3(512 / 32, 512 / 32), 256, 0, stream>>>(
            Wo + (size_t)i * DMODEL * DMODEL, wo_t, 512, 512);
        wconv_kernel<<<dim3(2048 / 32, 512 / 32), 256, 0, stream>>>(
            Wff1 + (size_t)i * DMODEL * FFD, w1_t, 512, 2048);
        wconv_kernel<<<dim3(512 / 32, 2048 / 32), 256, 0, stream>>>(
            Wff2 + (size_t)i * FFD * DMODEL, w2_t, 2048, 512);

        ln_kernel<<<NROWS, 256, 0, stream>>>(h, ln1_g + i * DMODEL, ln1_b + i * DMODEL, ybf);
        gemm_mfma<128, 128, 2, 4, 0, 0, 0, 0, 1><<<dim3(1536 / 128, NROWS / 128), 512, 0, stream>>>(
            ybf, wq_t, bqkv + i * 1536, nullptr, qkvb, Vt, 1536, 512);
        feat_kernel<1><<<512, 256, 0, stream>>>(qkvb, pj, nullptr, nullptr, kpart);
        kmax_reduce_kernel<<<16, 64, 0, stream>>>(kpart, kmaxb);
        feat_kernel<2><<<512, 256, 0, stream>>>(qkvb, pj, kmaxb, KPt, nullptr);
        ksum_kernel<<<4096, 256, 0, stream>>>(KPt, ksumb);
        feat_kernel<0><<<512, 256, 0, stream>>>(qkvb, pj, nullptr, QP, nullptr);
        ctx_gemm<<<dim3(16, 16), 256, 0, stream>>>(KPt, Vt, ctx_part);
        ctx_reduce_kernel<<<16, 256, 0, stream>>>(ctx_part, ctx_t);
        dinv_kernel<<<256, 256, 0, stream>>>(QP, ksumb, dinvb);
        out_gemm<<<dim3(32, 16), 256, 0, stream>>>(QP, ctx_t, dinvb, abufb);
        gemm_mfma<128, 64, 4, 2, 0, 1, 1, 0, 0><<<dim3(512 / 64, NROWS / 128), 512, 0, stream>>>(
            abufb, wo_t, bo + i * DMODEL, h, nullptr, nullptr, 512, 512);

        ln_kernel<<<NROWS, 256, 0, stream>>>(h, ln2_g + i * DMODEL, ln2_b + i * DMODEL, ybf);
        gemm_mfma<128, 128, 2, 4, 1, 0, 0, 1, 0><<<dim3(2048 / 128, NROWS / 128), 512, 0, stream>>>(
            ybf, w1_t, bff1 + i * FFD, nullptr, ffmidb, nullptr, 2048, 512);
        gemm_mfma<128, 64, 4, 2, 0, 1, 1, 0, 0><<<dim3(512 / 64, NROWS / 128), 512, 0, stream>>>(
            ffmidb, w2_t, bff2 + i * DMODEL, h, nullptr, nullptr, 512, 2048);
    }
}

// Round 5
// 958.747 us; speedup vs baseline: 6.3183x; 1.0519x over previous
//
#include <hip/hip_runtime.h>
#include <math.h>

#define DEPTH 4
#define DMODEL 512
#define DH 64
#define MF 256
#define FFD 2048
#define SEQN 4096
#define NROWS 8192

typedef __bf16 bf16_t;
typedef bf16_t bf16x8 __attribute__((ext_vector_type(8)));
typedef bf16_t bf16x4 __attribute__((ext_vector_type(4)));
typedef float f32x4v __attribute__((ext_vector_type(4)));

static constexpr float DN = 0.35355339059327373f;   // 64^-0.25
static constexpr float RATIO = 0.0625f;             // 256^-0.5
static constexpr float EPSK = 1e-4f;

__device__ __forceinline__ float gelu_exact(float x) {
    return 0.5f * x * (1.0f + erff(x * 0.70710678118654752f));
}

#define AS1(p) ((const __attribute__((address_space(1))) void*)(p))
#define AS3(p) ((__attribute__((address_space(3))) void*)(p))

// ---------------- LayerNorm -> bf16 ----------------
__global__ __launch_bounds__(256) void ln_kernel(const float* __restrict__ h,
                                                 const float* __restrict__ g,
                                                 const float* __restrict__ b,
                                                 bf16_t* __restrict__ y) {
    int row = blockIdx.x, tid = threadIdx.x;
    const float* hr = h + (size_t)row * DMODEL;
    float v0 = hr[tid], v1 = hr[tid + 256];
    __shared__ float s_sum[256], s_sq[256];
    s_sum[tid] = v0 + v1;
    s_sq[tid] = v0 * v0 + v1 * v1;
    __syncthreads();
    for (int off = 128; off > 0; off >>= 1) {
        if (tid < off) { s_sum[tid] += s_sum[tid + off]; s_sq[tid] += s_sq[tid + off]; }
        __syncthreads();
    }
    float mu = s_sum[0] * (1.0f / DMODEL);
    float var = s_sq[0] * (1.0f / DMODEL) - mu * mu;
    float rstd = rsqrtf(var + 1e-5f);
    bf16_t* yr = y + (size_t)row * DMODEL;
    yr[tid]       = (bf16_t)((v0 - mu) * rstd * g[tid] + b[tid]);
    yr[tid + 256] = (bf16_t)((v1 - mu) * rstd * g[tid + 256] + b[tid + 256]);
}

// ---------------- weight transpose + bf16 convert: Wt[N][K] = (bf16)W[K][N] ----------------
__global__ __launch_bounds__(256) void wconv_kernel(const float* __restrict__ W,
                                                    bf16_t* __restrict__ Wt, int K, int N) {
    __shared__ float t[32][33];
    int n0 = blockIdx.x * 32, k0 = blockIdx.y * 32;
    int tx = threadIdx.x & 31, ty = threadIdx.x >> 5;
#pragma unroll
    for (int i = 0; i < 32; i += 8)
        t[ty + i][tx] = W[(size_t)(k0 + ty + i) * N + n0 + tx];
    __syncthreads();
#pragma unroll
    for (int i = 0; i < 32; i += 8)
        Wt[(size_t)(n0 + ty + i) * K + k0 + tx] = (bf16_t)t[tx][ty + i];
}

// ---------------- proj -> bf16 (no transpose; proj is [m][dh] = [N][K]) ----------------
__global__ __launch_bounds__(256) void pconv_kernel(const float* __restrict__ proj,
                                                    bf16_t* __restrict__ projb) {
    int i = (blockIdx.x * 256 + threadIdx.x) * 4;
    float4 v = *(const float4*)(proj + i);
    bf16x4 o;
    o[0] = (bf16_t)v.x; o[1] = (bf16_t)v.y; o[2] = (bf16_t)v.z; o[3] = (bf16_t)v.w;
    *(bf16x4*)(projb + i) = o;
}

// ---------------- MFMA GEMM: C[M,N] = act(A[M,K] @ Bt[N,K]^T + bias) ----------------
// BMxBN tile, BK=32, 8 waves (WROWSxWCOLS), double-buffered LDS + prefetch (2-phase),
// XOR chunk swizzle on gload-source + ds_read, XCD-aware block remap (T1):
// blocks sharing an A-panel map to the SAME XCD so the panel is L2-fetched once per XCD.
template <int BM, int BN, int WROWS, int WCOLS, int ACT, int RES, int WF, int WB, int QKVE>
__global__ __launch_bounds__(512) void gemm_mfma(const bf16_t* __restrict__ A,
                                                 const bf16_t* __restrict__ Bt,
                                                 const float* __restrict__ bias,
                                                 float* __restrict__ Cf,
                                                 bf16_t* __restrict__ Cb,
                                                 bf16_t* __restrict__ Vt,
                                                 int N, int K) {
    constexpr int MR = BM / WROWS / 16;
    constexpr int NR = BN / WCOLS / 16;
    __shared__ __attribute__((aligned(16))) bf16_t As[2][BM * 32];
    __shared__ __attribute__((aligned(16))) bf16_t Bs[2][BN * 32];
    int tid = threadIdx.x;
    int wv = tid >> 6, ln = tid & 63;
    // XCD-aware remap (grid size is a multiple of 8 for all instantiations)
    int gx = gridDim.x;
    int lin = blockIdx.y * gx + blockIdx.x;
    int per = (gx * gridDim.y) >> 3;
    int orig = (lin & 7) * per + (lin >> 3);
    int m0 = (orig / gx) * BM, n0 = (orig % gx) * BN;
    int wr = (wv / WCOLS) * (MR * 16), wc = (wv % WCOLS) * (NR * 16);
    int lr = ln & 15, kq8 = ln >> 4;
    int arow = tid >> 2;
    int achunk = (tid & 3) ^ (arow & 3);   // inverse-swizzled source chunk
    const bf16_t* asrc0 = A + (size_t)(m0 + arow) * K + achunk * 8;
    const bf16_t* bsrc0 = Bt + (size_t)(n0 + arow) * K + achunk * 8;   // used if tid < BN*4
    f32x4v acc[MR][NR] = {};
    int nsteps = K / 32;
    // prologue: stage k-tile 0 into buf 0
    __builtin_amdgcn_global_load_lds(AS1(asrc0), AS3(&As[0][tid * 8]), 16, 0, 0);
    if (tid < BN * 4)
        __builtin_amdgcn_global_load_lds(AS1(bsrc0), AS3(&Bs[0][tid * 8]), 16, 0, 0);
    __syncthreads();
    for (int t = 0; t < nsteps; ++t) {
        int cur = t & 1;
        if (t + 1 < nsteps) {   // prefetch next k-tile into other buffer
            int k1 = (t + 1) * 32;
            __builtin_amdgcn_global_load_lds(AS1(asrc0 + k1), AS3(&As[cur ^ 1][tid * 8]), 16, 0, 0);
            if (tid < BN * 4)
                __builtin_amdgcn_global_load_lds(AS1(bsrc0 + k1), AS3(&Bs[cur ^ 1][tid * 8]), 16, 0, 0);
        }
        bf16x8 af[MR], bfr[NR];
#pragma unroll
        for (int m = 0; m < MR; m++) {
            int row = wr + m * 16 + lr;
            af[m] = *(const bf16x8*)&As[cur][row * 32 + ((kq8 ^ (row & 3)) * 8)];
        }
#pragma unroll
        for (int n = 0; n < NR; n++) {
            int row = wc + n * 16 + lr;
            bfr[n] = *(const bf16x8*)&Bs[cur][row * 32 + ((kq8 ^ (row & 3)) * 8)];
        }
#pragma unroll
        for (int m = 0; m < MR; m++)
#pragma unroll
            for (int n = 0; n < NR; n++)
                acc[m][n] = __builtin_amdgcn_mfma_f32_16x16x32_bf16(af[m], bfr[n], acc[m][n], 0, 0, 0);
        if (t + 1 < nsteps) __syncthreads();
    }
    int rq = (ln >> 4) * 4;
#pragma unroll
    for (int n = 0; n < NR; n++) {
        int col = n0 + wc + n * 16 + lr;
        float bcol = bias[col];
#pragma unroll
        for (int m = 0; m < MR; m++) {
#pragma unroll
            for (int r = 0; r < 4; r++) {
                int row = m0 + wr + m * 16 + rq + r;
                float v = acc[m][n][r] + bcol;
                if (ACT == 1) v = gelu_exact(v);
                if (QKVE) {
                    int bb = row >> 12, nn = row & 4095;
                    if (col < 1024) {
                        Cb[(size_t)row * 1024 + col] = (bf16_t)v;
                    } else {
                        int hh2 = (col >> 6) & 7, dd2 = col & 63;
                        Vt[(((size_t)bb * 8 + hh2) * 64 + dd2) * 4096 + nn] = (bf16_t)v;
                    }
                } else {
                    size_t idx = (size_t)row * N + col;
                    if (RES) Cf[idx] += v;
                    else if (WF) Cf[idx] = v;
                    if (WB) Cb[idx] = (bf16_t)v;
                }
            }
        }
    }
}

// ---------------- FAVOR+ feature GEMM: dd[128n x 256m] per block, K=64 ----------------
// MODE 0 = Q (rowmax+exp -> QP[bh][n][m] bf16)
// MODE 1 = K max pass (block max of dd -> kpart)
// MODE 2 = K write pass (exp with kmx -> KPt[bh][m][n] bf16, transposed)
template <int MODE>
__global__ __launch_bounds__(256) void feat_kernel(const bf16_t* __restrict__ qkvb,
                                                   const bf16_t* __restrict__ projb,
                                                   const float* __restrict__ kmaxb,
                                                   bf16_t* __restrict__ outp,
                                                   float* __restrict__ kpart) {
    int bid = blockIdx.x;
    int bh = bid >> 5, tile = bid & 31;
    int b = bh >> 3, hh = bh & 7;
    int tid = threadIdx.x, wv = tid >> 6, ln = tid & 63;
    __shared__ __attribute__((aligned(16))) bf16_t As[128 * 64];
    __shared__ __attribute__((aligned(16))) bf16_t Bs[256 * 64];
    __shared__ float diag_s[128];
    __shared__ float rmx_s[2][128];
    __shared__ float red_s[256];
    int n0 = tile * 128;
    int qoff = (MODE == 0 ? 0 : 512) + hh * 64;
    int lrow8 = ln >> 3;
    int lchunk = ((ln & 7) ^ (lrow8 & 7)) * 8;   // pre-swizzled source chunk
#pragma unroll
    for (int i = 0; i < 4; i++) {
        int e = wv * 4 + i;
        size_t src = (size_t)(b * SEQN + n0 + e * 8 + lrow8) * 1024 + qoff + lchunk;
        __builtin_amdgcn_global_load_lds(AS1(qkvb + src), AS3(&As[e * 512]), 16, 0, 0);
    }
#pragma unroll
    for (int i = 0; i < 8; i++) {
        int e = wv * 8 + i;
        size_t src = (size_t)(e * 8 + lrow8) * 64 + lchunk;
        __builtin_amdgcn_global_load_lds(AS1(projb + src), AS3(&Bs[e * 512]), 16, 0, 0);
    }
    __syncthreads();
    if (MODE != 1 && tid < 128) {
        float s = 0.f;
#pragma unroll
        for (int c = 0; c < 8; c++) {
            bf16x8 v = *(const bf16x8*)&As[tid * 64 + ((c ^ (tid & 7)) * 8)];
#pragma unroll
            for (int j = 0; j < 8; j++) { float f = (float)v[j]; s += f * f; }
        }
        diag_s[tid] = s * (0.5f * DN * DN);
    }
    int wr = (wv >> 1) * 64, wc = (wv & 1) * 128;
    int lr = ln & 15, kg = ln >> 4, rq = kg * 4;
    f32x4v acc[4][8] = {};
#pragma unroll
    for (int ks = 0; ks < 2; ks++) {
        int g = ks * 4 + kg;
        bf16x8 af[4], bfv[8];
#pragma unroll
        for (int m = 0; m < 4; m++) {
            int row = wr + m * 16 + lr;
            af[m] = *(const bf16x8*)&As[row * 64 + ((g ^ (row & 7)) * 8)];
        }
#pragma unroll
        for (int n = 0; n < 8; n++) {
            int row = wc + n * 16 + lr;
            bfv[n] = *(const bf16x8*)&Bs[row * 64 + ((g ^ (row & 7)) * 8)];
        }
#pragma unroll
        for (int m = 0; m < 4; m++)
#pragma unroll
            for (int n = 0; n < 8; n++)
                acc[m][n] = __builtin_amdgcn_mfma_f32_16x16x32_bf16(af[m], bfv[n], acc[m][n], 0, 0, 0);
    }
    if (MODE == 1) {
        float mx = -1e30f;
#pragma unroll
        for (int m = 0; m < 4; m++)
#pragma unroll
            for (int n = 0; n < 8; n++)
#pragma unroll
                for (int r = 0; r < 4; r++) mx = fmaxf(mx, acc[m][n][r]);
        red_s[tid] = mx * DN;
        __syncthreads();
        for (int off = 128; off > 0; off >>= 1) {
            if (tid < off) red_s[tid] = fmaxf(red_s[tid], red_s[tid + off]);
            __syncthreads();
        }
        if (tid == 0) kpart[bid] = red_s[0];
    } else if (MODE == 2) {
        float kmx = kmaxb[bh];
        __syncthreads();   // diag_s visible
#pragma unroll
        for (int m = 0; m < 4; m++) {
#pragma unroll
            for (int n = 0; n < 8; n++) {
                int col = wc + n * 16 + lr;
                bf16x4 pk;
#pragma unroll
                for (int r = 0; r < 4; r++) {
                    int row = wr + m * 16 + rq + r;
                    pk[r] = (bf16_t)(RATIO * (expf(acc[m][n][r] * DN - diag_s[row] - kmx) + EPSK));
                }
                *(bf16x4*)&outp[((size_t)bh * MF + col) * 4096 + n0 + wr + m * 16 + rq] = pk;
            }
        }
    } else {
        float pmax[4][4];
#pragma unroll
        for (int m = 0; m < 4; m++)
#pragma unroll
            for (int r = 0; r < 4; r++) {
                float mx = acc[m][0][r];
#pragma unroll
                for (int n = 1; n < 8; n++) mx = fmaxf(mx, acc[m][n][r]);
#pragma unroll
                for (int mask = 1; mask < 16; mask <<= 1)
                    mx = fmaxf(mx, __shfl_xor(mx, mask));
                pmax[m][r] = mx;
            }
        if (lr == 0) {
#pragma unroll
            for (int m = 0; m < 4; m++)
#pragma unroll
                for (int r = 0; r < 4; r++)
                    rmx_s[wv & 1][wr + m * 16 + rq + r] = pmax[m][r] * DN;
        }
        __syncthreads();
#pragma unroll
        for (int m = 0; m < 4; m++) {
#pragma unroll
            for (int r = 0; r < 4; r++) {
                int row = wr + m * 16 + rq + r;
                float rm = fmaxf(rmx_s[0][row], rmx_s[1][row]);
                float dg = diag_s[row];
                size_t obase = ((size_t)bh * SEQN + n0 + row) * MF;
#pragma unroll
                for (int n = 0; n < 8; n++) {
                    float val = RATIO * (expf(acc[m][n][r] * DN - dg - rm) + EPSK);
                    outp[obase + wc + n * 16 + lr] = (bf16_t)val;
                }
            }
        }
    }
}

__global__ __launch_bounds__(64) void kmax_reduce_kernel(const float* __restrict__ part,
                                                         float* __restrict__ kmax) {
    int bh = blockIdx.x, tid = threadIdx.x;
    float v = (tid < 32) ? part[bh * 32 + tid] : -1e30f;
#pragma unroll
    for (int off = 16; off > 0; off >>= 1) v = fmaxf(v, __shfl_down(v, off));
    if (tid == 0) kmax[bh] = v;
}

// ---------------- ksum: row sums of KPt ----------------
__global__ __launch_bounds__(256) void ksum_kernel(const bf16_t* __restrict__ KPt,
                                                   float* __restrict__ ksum) {
    int row = blockIdx.x, tid = threadIdx.x;
    const bf16_t* r = KPt + (size_t)row * 4096;
    float s = 0.f;
#pragma unroll
    for (int i = 0; i < 2; i++) {
        bf16x8 v = *(const bf16x8*)&r[tid * 16 + i * 8];
#pragma unroll
        for (int j = 0; j < 8; j++) s += (float)v[j];
    }
    __shared__ float red[256];
    red[tid] = s; __syncthreads();
    for (int off = 128; off > 0; off >>= 1) {
        if (tid < off) red[tid] += red[tid + off];
        __syncthreads();
    }
    if (tid == 0) ksum[row] = red[0];
}

// ---------------- ctx split-K GEMM: part[kc][bh][m][d] = KPt-chunk @ Vt-chunk^T ----------------
__global__ __launch_bounds__(256) void ctx_gemm(const bf16_t* __restrict__ KPt,
                                                const bf16_t* __restrict__ Vt,
                                                float* __restrict__ part) {
    int bh = blockIdx.y;
    int mtile = blockIdx.x & 1, kc = blockIdx.x >> 1;
    int m0 = mtile * 128, nb = kc * 512;
    int tid = threadIdx.x, wv = tid >> 6, ln = tid & 63;
    __shared__ __attribute__((aligned(16))) bf16_t As[128 * 64];
    __shared__ __attribute__((aligned(16))) bf16_t Bs[64 * 64];
    int lrow8 = ln >> 3;
    int lchunk = ((ln & 7) ^ (lrow8 & 7)) * 8;
    int lr = ln & 15, kg = ln >> 4, rq = kg * 4;
    int wr = wv * 32;
    f32x4v acc[2][4] = {};
    for (int kt = 0; kt < 8; kt++) {
        int noff = nb + kt * 64;
        __syncthreads();
#pragma unroll
        for (int i = 0; i < 4; i++) {
            int e = wv * 4 + i;
            __builtin_amdgcn_global_load_lds(
                AS1(KPt + ((size_t)bh * MF + m0 + e * 8 + lrow8) * 4096 + noff + lchunk),
                AS3(&As[e * 512]), 16, 0, 0);
        }
#pragma unroll
        for (int i = 0; i < 2; i++) {
            int e = wv * 2 + i;
            __builtin_amdgcn_global_load_lds(
                AS1(Vt + ((size_t)bh * 64 + e * 8 + lrow8) * 4096 + noff + lchunk),
                AS3(&Bs[e * 512]), 16, 0, 0);
        }
        __syncthreads();
#pragma unroll
        for (int ks = 0; ks < 2; ks++) {
            int g = ks * 4 + kg;
            bf16x8 af[2], bfv[4];
#pragma unroll
            for (int m = 0; m < 2; m++) {
                int row = wr + m * 16 + lr;
                af[m] = *(const bf16x8*)&As[row * 64 + ((g ^ (row & 7)) * 8)];
            }
#pragma unroll
            for (int n = 0; n < 4; n++) {
                int row = n * 16 + lr;
                bfv[n] = *(const bf16x8*)&Bs[row * 64 + ((g ^ (row & 7)) * 8)];
            }
#pragma unroll
            for (int m = 0; m < 2; m++)
#pragma unroll
                for (int n = 0; n < 4; n++)
                    acc[m][n] = __builtin_amdgcn_mfma_f32_16x16x32_bf16(af[m], bfv[n], acc[m][n], 0, 0, 0);
        }
    }
#pragma unroll
    for (int m = 0; m < 2; m++)
#pragma unroll
        for (int n = 0; n < 4; n++)
#pragma unroll
            for (int r = 0; r < 4; r++)
                part[((size_t)(kc * 16 + bh) * MF + m0 + wr + m * 16 + rq + r) * 64 + n * 16 + lr] =
                    acc[m][n][r];
}

// ---------------- ctx reduce (8 partials) -> ctx_t[bh][d][m] bf16 ----------------
__global__ __launch_bounds__(256) void ctx_reduce_kernel(const float* __restrict__ part,
                                                         bf16_t* __restrict__ ctx_t) {
    int bh = blockIdx.x;
    for (int it = 0; it < 64; it++) {
        int idx = it * 256 + threadIdx.x;
        int m = idx >> 6, d = idx & 63;
        float s = 0.f;
#pragma unroll
        for (int kc = 0; kc < 8; kc++)
            s += part[(size_t)(kc * 16 + bh) * 16384 + idx];
        ctx_t[((size_t)bh * 64 + d) * MF + m] = (bf16_t)s;
    }
}

// ---------------- dinv[bh][n] = 1 / (QP[n,:] . ksum[bh,:]) ----------------
__global__ __launch_bounds__(256) void dinv_kernel(const bf16_t* __restrict__ QP,
                                                   const float* __restrict__ ksum,
                                                   float* __restrict__ dinv) {
    int bid = blockIdx.x, tid = threadIdx.x;
    int bh = bid >> 4;
    __shared__ float ks[256];
    ks[tid] = ksum[bh * MF + tid];
    __syncthreads();
    size_t row = (size_t)bid * 256 + tid;
    const bf16_t* q = QP + row * MF;
    float s = 0.f;
#pragma unroll
    for (int i = 0; i < 32; i++) {
        bf16x8 v = *(const bf16x8*)&q[i * 8];
#pragma unroll
        for (int j = 0; j < 8; j++) s += (float)v[j] * ks[i * 8 + j];
    }
    dinv[row] = 1.0f / s;
}

// ---------------- out GEMM: abuf[n][h*64+d] = (QP @ ctx_t^T)[n][d] * dinv[n] ----------------
__global__ __launch_bounds__(256) void out_gemm(const bf16_t* __restrict__ QP,
                                                const bf16_t* __restrict__ ctx_t,
                                                const float* __restrict__ dinv,
                                                bf16_t* __restrict__ abuf) {
    int bh = blockIdx.y, ntile = blockIdx.x;
    int b = bh >> 3, hh = bh & 7;
    int n0 = ntile * 128;
    int tid = threadIdx.x, wv = tid >> 6, ln = tid & 63;
    __shared__ __attribute__((aligned(16))) bf16_t As[128 * 64];
    __shared__ __attribute__((aligned(16))) bf16_t Bs[64 * 64];
    int lrow8 = ln >> 3;
    int lchunk = ((ln & 7) ^ (lrow8 & 7)) * 8;
    int lr = ln & 15, kg = ln >> 4, rq = kg * 4;
    int wr = wv * 32;
    f32x4v acc[2][4] = {};
    for (int kt = 0; kt < 4; kt++) {
        int koff = kt * 64;
        __syncthreads();
#pragma unroll
        for (int i = 0; i < 4; i++) {
            int e = wv * 4 + i;
            __builtin_amdgcn_global_load_lds(
                AS1(QP + ((size_t)bh * SEQN + n0 + e * 8 + lrow8) * MF + koff + lchunk),
                AS3(&As[e * 512]), 16, 0, 0);
        }
#pragma unroll
        for (int i = 0; i < 2; i++) {
            int e = wv * 2 + i;
            __builtin_amdgcn_global_load_lds(
                AS1(ctx_t + ((size_t)bh * 64 + e * 8 + lrow8) * MF + koff + lchunk),
                AS3(&Bs[e * 512]), 16, 0, 0);
        }
        __syncthreads();
#pragma unroll
        for (int ks = 0; ks < 2; ks++) {
            int g = ks * 4 + kg;
            bf16x8 af[2], bfv[4];
#pragma unroll
            for (int m = 0; m < 2; m++) {
                int row = wr + m * 16 + lr;
                af[m] = *(const bf16x8*)&As[row * 64 + ((g ^ (row & 7)) * 8)];
            }
#pragma unroll
            for (int n = 0; n < 4; n++) {
                int row = n * 16 + lr;
                bfv[n] = *(const bf16x8*)&Bs[row * 64 + ((g ^ (row & 7)) * 8)];
            }
#pragma unroll
            for (int m = 0; m < 2; m++)
#pragma unroll
                for (int n = 0; n < 4; n++)
                    acc[m][n] = __builtin_amdgcn_mfma_f32_16x16x32_bf16(af[m], bfv[n], acc[m][n], 0, 0, 0);
        }
    }
#pragma unroll
    for (int m = 0; m < 2; m++) {
#pragma unroll
        for (int r = 0; r < 4; r++) {
            int row = n0 + wr + m * 16 + rq + r;
            float di = dinv[(size_t)bh * SEQN + row];
#pragma unroll
            for (int n = 0; n < 4; n++)
                abuf[((size_t)b * SEQN + row) * DMODEL + hh * 64 + n * 16 + lr] =
                    (bf16_t)(acc[m][n][r] * di);
        }
    }
}

extern "C" void kernel_launch(void* const* d_in, const int* in_sizes, int n_in,
                              void* d_out, int out_size, void* d_ws, size_t ws_size,
                              hipStream_t stream) {
    const float* x     = (const float*)d_in[0];
    const float* proj  = (const float*)d_in[1];
    const float* ln1_g = (const float*)d_in[2];
    const float* ln1_b = (const float*)d_in[3];
    const float* Wqkv  = (const float*)d_in[4];
    const float* bqkv  = (const float*)d_in[5];
    const float* Wo    = (const float*)d_in[6];
    const float* bo    = (const float*)d_in[7];
    const float* ln2_g = (const float*)d_in[8];
    const float* ln2_b = (const float*)d_in[9];
    const float* Wff1  = (const float*)d_in[10];
    const float* bff1  = (const float*)d_in[11];
    const float* Wff2  = (const float*)d_in[12];
    const float* bff2  = (const float*)d_in[13];

    float* h = (float*)d_out;
    char* ws = (char*)d_ws;
    // Region 0: KPt (32Mi). ybf aliases its first 8Mi (dead before KPt written; ln2 after ctx).
    bf16_t* KPt   = (bf16_t*)(ws);
    bf16_t* ybf   = (bf16_t*)(ws);
    // Region 1: qkvb Q+K [8192][1024] (16Mi). abuf aliases [0,8Mi); ctx_part aliases [8Mi,16Mi).
    bf16_t* qkvb  = (bf16_t*)(ws + 33554432);
    bf16_t* abufb = (bf16_t*)(ws + 33554432);
    float*  ctx_part = (float*)(ws + 33554432 + 8388608);
    // Region 2: QP (32Mi). ffmid aliases (dead after out_gemm/dinv).
    bf16_t* QP    = (bf16_t*)(ws + 50331648);
    bf16_t* ffmidb= (bf16_t*)(ws + 50331648);
    // Region 3: Vt (8Mi)
    bf16_t* Vt    = (bf16_t*)(ws + 83886080);
    // Region 4: weights + small
    bf16_t* wq_t  = (bf16_t*)(ws + 92274688);   // 1536*512*2
    bf16_t* wo_t  = (bf16_t*)(ws + 93847552);   // 512*512*2
    bf16_t* w1_t  = (bf16_t*)(ws + 94371840);   // 2048*512*2
    bf16_t* w2_t  = (bf16_t*)(ws + 96468992);   // 512*2048*2
    bf16_t* projb = (bf16_t*)(ws + 98566144);   // 4*256*64*2
    bf16_t* ctx_t = (bf16_t*)(ws + 98697216);   // 16*64*256*2
    float*  ksumb = (float*)(ws + 99221504);    // 4096*4
    float*  dinvb = (float*)(ws + 99237888);    // 65536*4
    float*  kpart = (float*)(ws + 99500032);    // 512*4
    float*  kmaxb = (float*)(ws + 99502080);    // 16*4

    hipMemcpyAsync(h, x, (size_t)NROWS * DMODEL * sizeof(float),
                   hipMemcpyDeviceToDevice, stream);
    pconv_kernel<<<64, 256, 0, stream>>>(proj, projb);

    for (int i = 0; i < DEPTH; i++) {
        const bf16_t* pj = projb + (size_t)i * MF * DH;
        wconv_kernel<<<dim3(1536 / 32, 512 / 32), 256, 0, stream>>>(
            Wqkv + (size_t)i * DMODEL * 1536, wq_t, 512, 1536);
        wconv_kernel<<<dim3(512 / 32, 512 / 32), 256, 0, stream>>>(
            Wo + (size_t)i * DMODEL * DMODEL, wo_t, 512, 512);
        wconv_kernel<<<dim3(2048 / 32, 512 / 32), 256, 0, stream>>>(
            Wff1 + (size_t)i * DMODEL * FFD, w1_t, 512, 2048);
        wconv_kernel<<<dim3(512 / 32, 2048 / 32), 256, 0, stream>>>(
            Wff2 + (size_t)i * FFD * DMODEL, w2_t, 2048, 512);

        ln_kernel<<<NROWS, 256, 0, stream>>>(h, ln1_g + i * DMODEL, ln1_b + i * DMODEL, ybf);
        gemm_mfma<128, 128, 2, 4, 0, 0, 0, 0, 1><<<dim3(1536 / 128, NROWS / 128), 512, 0, stream>>>(
            ybf, wq_t, bqkv + i * 1536, nullptr, qkvb, Vt, 1536, 512);
        feat_kernel<1><<<512, 256, 0, stream>>>(qkvb, pj, nullptr, nullptr, kpart);
        kmax_reduce_kernel<<<16, 64, 0, stream>>>(kpart, kmaxb);
        feat_kernel<2><<<512, 256, 0, stream>>>(qkvb, pj, kmaxb, KPt, nullptr);
        ksum_kernel<<<4096, 256, 0, stream>>>(KPt, ksumb);
        feat_kernel<0><<<512, 256, 0, stream>>>(qkvb, pj, nullptr, QP, nullptr);
        ctx_gemm<<<dim3(16, 16), 256, 0, stream>>>(KPt, Vt, ctx_part);
        ctx_reduce_kernel<<<16, 256, 0, stream>>>(ctx_part, ctx_t);
        dinv_kernel<<<256, 256, 0, stream>>>(QP, ksumb, dinvb);
        out_gemm<<<dim3(32, 16), 256, 0, stream>>>(QP, ctx_t, dinvb, abufb);
        gemm_mfma<128, 64, 4, 2, 0, 1, 1, 0, 0><<<dim3(512 / 64, NROWS / 128), 512, 0, stream>>>(
            abufb, wo_t, bo + i * DMODEL, h, nullptr, nullptr, 512, 512);

        ln_kernel<<<NROWS, 256, 0, stream>>>(h, ln2_g + i * DMODEL, ln2_b + i * DMODEL, ybf);
        gemm_mfma<128, 128, 2, 4, 1, 0, 0, 1, 0><<<dim3(2048 / 128, NROWS / 128), 512, 0, stream>>>(
            ybf, w1_t, bff1 + i * FFD, nullptr, ffmidb, nullptr, 2048, 512);
        gemm_mfma<128, 64, 4, 2, 0, 1, 1, 0, 0><<<dim3(512 / 64, NROWS / 128), 512, 0, stream>>>(
            ffmidb, w2_t, bff2 + i * DMODEL, h, nullptr, nullptr, 512, 2048);
    }
}